// Round 1
// baseline (3036.230 us; speedup 1.0000x reference)
//
#include <hip/hip_runtime.h>
#include <math.h>

#define NELEM 8388608   // B*T*D*H*W = 2*16*64*64*64
#define HW    4096
#define DCH   64
#define TT    16
#define BTN   32        // B*T
#define EPS   1e-5f

__device__ __forceinline__ int rev6(int x) {
  return ((x & 1) << 5) | ((x & 2) << 3) | ((x & 4) << 1) |
         ((x & 8) >> 1) | ((x & 16) >> 3) | ((x & 32) >> 5);
}

// ---------------- Kernel A: spatial complex-norm (LN over 2D=128 feats) ----
__global__ __launch_bounds__(256) void k_ln_spatial(
    const float* __restrict__ xr, const float* __restrict__ xi,
    const float* __restrict__ w, const float* __restrict__ b,
    float* __restrict__ outr, float* __restrict__ outi) {
  int gid = blockIdx.x * 256 + threadIdx.x;   // 0..131071 = BT*HW
  int bt = gid >> 12;
  int hw = gid & 4095;
  int base = bt * DCH * HW + hw;
  float vr[DCH], vi[DCH];
  float s = 0.f, s2 = 0.f;
#pragma unroll
  for (int d = 0; d < DCH; ++d) {
    float a = xr[base + d * HW];
    float c = xi[base + d * HW];
    vr[d] = a; vi[d] = c;
    s += a + c;
    s2 += a * a + c * c;
  }
  float mu = s * (1.f / 128.f);
  float var = s2 * (1.f / 128.f) - mu * mu;
  float rs = rsqrtf(var + EPS);
#pragma unroll
  for (int d = 0; d < DCH; ++d) {
    outr[base + d * HW] = (vr[d] - mu) * rs * w[d] + b[d];
    outi[base + d * HW] = (vi[d] - mu) * rs * w[64 + d] + b[64 + d];
  }
}

// ---------------- Kernel B: 3x3 complex conv (cross-correlation, SAME) -----
__global__ __launch_bounds__(256) void k_conv(
    const float* __restrict__ xr, const float* __restrict__ xi,
    const float* __restrict__ wr, const float* __restrict__ wi,
    const float* __restrict__ br, const float* __restrict__ bi,
    float* __restrict__ outr, float* __restrict__ outi) {
  __shared__ float tr[18 * 18], ti[18 * 18];
  int bid = blockIdx.x;
  int tw = bid & 3, th = (bid >> 2) & 3, dout = (bid >> 4) & 63, n = bid >> 10;
  int h0 = th * 16, w0 = tw * 16;
  int tid = threadIdx.x;
  int ty = tid >> 4, tx = tid & 15;
  float accr = 0.f, acci = 0.f;
  const float* wrp = wr + dout * DCH * 9;
  const float* wip = wi + dout * DCH * 9;
  for (int din = 0; din < DCH; ++din) {
    __syncthreads();
    for (int idx = tid; idx < 324; idx += 256) {
      int rr = idx / 18, cc = idx - rr * 18;
      int gh = h0 + rr - 1, gw = w0 + cc - 1;
      float a = 0.f, c = 0.f;
      if (gh >= 0 && gh < 64 && gw >= 0 && gw < 64) {
        int ad = ((n * DCH + din) * 64 + gh) * 64 + gw;
        a = xr[ad]; c = xi[ad];
      }
      tr[idx] = a; ti[idx] = c;
    }
    __syncthreads();
    const float* wr9 = wrp + din * 9;
    const float* wi9 = wip + din * 9;
#pragma unroll
    for (int kh = 0; kh < 3; ++kh) {
#pragma unroll
      for (int kw = 0; kw < 3; ++kw) {
        float a = tr[(ty + kh) * 18 + tx + kw];
        float c = ti[(ty + kh) * 18 + tx + kw];
        float wwr = wr9[kh * 3 + kw], wwi = wi9[kh * 3 + kw];
        accr += a * wwr - c * wwi;
        acci += a * wwi + c * wwr;
      }
    }
  }
  int oa = ((n * DCH + dout) * 64 + (h0 + ty)) * 64 + (w0 + tx);
  outr[oa] = accr + br[dout];
  outi[oa] = acci + bi[dout];
}

// -------- Kernel C: FFT2 -> wspec -> iFFT2, blend with cliff + resid -------
__global__ __launch_bounds__(256) void k_fft_blend(
    float* __restrict__ Xr, float* __restrict__ Xi,        // W0 in/out
    const float* __restrict__ cr, const float* __restrict__ ci,
    const float* __restrict__ rr_, const float* __restrict__ ri_,
    const float* __restrict__ swr, const float* __restrict__ swi,
    const float* __restrict__ gate) {
  __shared__ float sr[64 * 65], si[64 * 65];
  const float PI = 3.14159265358979323846f;
  int bid = blockIdx.x;
  int ch = bid & 63;
  int base = bid << 12;
  int tid = threadIdx.x;
  for (int idx = tid; idx < 4096; idx += 256) {
    int r = idx >> 6, c = idx & 63;
    sr[r * 65 + c] = Xr[base + idx];
    si[r * 65 + c] = Xi[base + idx];
  }
  // forward rows, DIF (natural in, bit-reversed out)
  for (int s = 5; s >= 0; --s) {
    int half = 1 << s;
    __syncthreads();
    for (int idx = tid; idx < 2048; idx += 256) {
      int r = idx >> 5, j = idx & 31;
      int k = j & (half - 1), g = j >> s;
      int i0 = (g << (s + 1)) + k, i1 = i0 + half;
      float sv, cv; __sincosf(-PI * k / half, &sv, &cv);
      float ur = sr[r * 65 + i0], ui = si[r * 65 + i0];
      float vr = sr[r * 65 + i1], vi = si[r * 65 + i1];
      sr[r * 65 + i0] = ur + vr; si[r * 65 + i0] = ui + vi;
      float dr = ur - vr, di = ui - vi;
      sr[r * 65 + i1] = dr * cv - di * sv;
      si[r * 65 + i1] = dr * sv + di * cv;
    }
  }
  // forward cols, DIF
  for (int s = 5; s >= 0; --s) {
    int half = 1 << s;
    __syncthreads();
    for (int idx = tid; idx < 2048; idx += 256) {
      int c = idx & 63, j = idx >> 6;
      int k = j & (half - 1), g = j >> s;
      int i0 = (g << (s + 1)) + k, i1 = i0 + half;
      float sv, cv; __sincosf(-PI * k / half, &sv, &cv);
      float ur = sr[i0 * 65 + c], ui = si[i0 * 65 + c];
      float vr = sr[i1 * 65 + c], vi = si[i1 * 65 + c];
      sr[i0 * 65 + c] = ur + vr; si[i0 * 65 + c] = ui + vi;
      float dr = ur - vr, di = ui - vi;
      sr[i1 * 65 + c] = dr * cv - di * sv;
      si[i1 * 65 + c] = dr * sv + di * cv;
    }
  }
  __syncthreads();
  // multiply by wspec; LDS[r][c] = F[rev r][rev c]
  for (int idx = tid; idx < 4096; idx += 256) {
    int r = idx >> 6, c = idx & 63;
    int fr = rev6(r), fc = rev6(c);
    float wr = swr[ch * 4096 + fr * 64 + fc];
    float wi = swi[ch * 4096 + fr * 64 + fc];
    float a = sr[r * 65 + c], b = si[r * 65 + c];
    sr[r * 65 + c] = a * wr - b * wi;
    si[r * 65 + c] = a * wi + b * wr;
  }
  // inverse cols, DIT (bit-reversed in, natural out), conj twiddle
  for (int s = 0; s <= 5; ++s) {
    int half = 1 << s;
    __syncthreads();
    for (int idx = tid; idx < 2048; idx += 256) {
      int c = idx & 63, j = idx >> 6;
      int k = j & (half - 1), g = j >> s;
      int i0 = (g << (s + 1)) + k, i1 = i0 + half;
      float sv, cv; __sincosf(PI * k / half, &sv, &cv);
      float vr = sr[i1 * 65 + c], vi = si[i1 * 65 + c];
      float tr2 = vr * cv - vi * sv;
      float ti2 = vr * sv + vi * cv;
      float ur = sr[i0 * 65 + c], ui = si[i0 * 65 + c];
      sr[i0 * 65 + c] = ur + tr2; si[i0 * 65 + c] = ui + ti2;
      sr[i1 * 65 + c] = ur - tr2; si[i1 * 65 + c] = ui - ti2;
    }
  }
  // inverse rows, DIT
  for (int s = 0; s <= 5; ++s) {
    int half = 1 << s;
    __syncthreads();
    for (int idx = tid; idx < 2048; idx += 256) {
      int r = idx >> 5, j = idx & 31;
      int k = j & (half - 1), g = j >> s;
      int i0 = (g << (s + 1)) + k, i1 = i0 + half;
      float sv, cv; __sincosf(PI * k / half, &sv, &cv);
      float vr = sr[r * 65 + i1], vi = si[r * 65 + i1];
      float tr2 = vr * cv - vi * sv;
      float ti2 = vr * sv + vi * cv;
      float ur = sr[r * 65 + i0], ui = si[r * 65 + i0];
      sr[r * 65 + i0] = ur + tr2; si[r * 65 + i0] = ui + ti2;
      sr[r * 65 + i1] = ur - tr2; si[r * 65 + i1] = ui - ti2;
    }
  }
  __syncthreads();
  float g = gate[0];
  const float scale = 1.f / 4096.f;
  for (int idx = tid; idx < 4096; idx += 256) {
    int r = idx >> 6, c = idx & 63;
    float spr = sr[r * 65 + c] * scale, spi = si[r * 65 + c] * scale;
    int a = base + idx;
    Xr[a] = g * cr[a] + (1.f - g) * spr + rr_[a];
    Xi[a] = g * ci[a] + (1.f - g) * spi + ri_[a];
  }
}

// -------- Kernel D: temporal cnorm + eig proj + scan + back proj -----------
__global__ __launch_bounds__(256) void k_temporal(
    float* __restrict__ Xr, float* __restrict__ Xi,   // W0 in/out
    const float* __restrict__ dt,
    const float* __restrict__ lnw, const float* __restrict__ lnb,
    const float* __restrict__ lam_re, const float* __restrict__ lam_im,
    const float* __restrict__ V_re, const float* __restrict__ V_im,
    const float* __restrict__ Vi_re, const float* __restrict__ Vi_im) {
  __shared__ float xnr[16 * 65], xni[16 * 65];
  __shared__ float er[16 * 65], ei[16 * 65];
  __shared__ float Wr[64 * 65], Wi[64 * 65];   // Vinv
  __shared__ float Vr[64 * 65], Vm[64 * 65];   // V
  __shared__ float mu_s[16], rs_s[16];
  int bid = blockIdx.x;
  int b = bid >> 12;
  int hw = bid & 4095;
  int tid = threadIdx.x;
  for (int idx = tid; idx < 4096; idx += 256) {
    int r = idx >> 6, k = idx & 63;
    Wr[r * 65 + k] = Vi_re[idx]; Wi[r * 65 + k] = Vi_im[idx];
    Vr[r * 65 + k] = V_re[idx];  Vm[r * 65 + k] = V_im[idx];
  }
  int base = b * TT * DCH * HW + hw;       // addr(t,d) = base + (t*64+d)*4096
  for (int idx = tid; idx < 1024; idx += 256) {
    int t = idx >> 6, d = idx & 63;
    xnr[t * 65 + d] = Xr[base + idx * HW];
    xni[t * 65 + d] = Xi[base + idx * HW];
  }
  __syncthreads();
  if (tid < 16) {
    float s = 0.f, s2 = 0.f;
    for (int d = 0; d < 64; ++d) {
      float a = xnr[tid * 65 + d], c = xni[tid * 65 + d];
      s += a + c; s2 += a * a + c * c;
    }
    float mu = s * (1.f / 128.f);
    float var = s2 * (1.f / 128.f) - mu * mu;
    mu_s[tid] = mu; rs_s[tid] = rsqrtf(var + EPS);
  }
  __syncthreads();
  for (int idx = tid; idx < 1024; idx += 256) {
    int t = idx >> 6, d = idx & 63;
    xnr[t * 65 + d] = (xnr[t * 65 + d] - mu_s[t]) * rs_s[t] * lnw[d] + lnb[d];
    xni[t * 65 + d] = (xni[t * 65 + d] - mu_s[t]) * rs_s[t] * lnw[64 + d] + lnb[64 + d];
  }
  __syncthreads();
  int dd = tid & 63, tq = tid >> 6;
#pragma unroll
  for (int q = 0; q < 4; ++q) {
    int t = q * 4 + tq;
    float ar = 0.f, ai = 0.f;
    for (int k = 0; k < 64; ++k) {
      float a = xnr[t * 65 + k], c = xni[t * 65 + k];
      float br = Wr[dd * 65 + k], bi = Wi[dd * 65 + k];
      ar += a * br - c * bi;
      ai += a * bi + c * br;
    }
    er[t * 65 + dd] = ar; ei[t * 65 + dd] = ai;
  }
  __syncthreads();
  if (tid < 64) {
    int d = tid;
    float x0 = lam_re[d];
    float nl = -(x0 > 15.f ? x0 : log1pf(__expf(x0)));   // -softplus
    float li = lam_im[d];
    float hr = 0.f, hi = 0.f;
    for (int t = 0; t < 16; ++t) {
      float dtv = dt[b * 16 + t];
      float ea = __expf(nl * dtv);
      float sv, cv; __sincosf(li * dtv, &sv, &cv);
      float evr = ea * cv, evi = ea * sv;
      float nr = evr * hr - evi * hi + er[t * 65 + d];
      float ni = evr * hi + evi * hr + ei[t * 65 + d];
      hr = nr; hi = ni;
      er[t * 65 + d] = hr; ei[t * 65 + d] = hi;
    }
  }
  __syncthreads();
#pragma unroll
  for (int q = 0; q < 4; ++q) {
    int t = q * 4 + tq;
    float ar = 0.f, ai = 0.f;
    for (int k = 0; k < 64; ++k) {
      float a = er[t * 65 + k], c = ei[t * 65 + k];
      float br = Vr[dd * 65 + k], bi = Vm[dd * 65 + k];
      ar += a * br - c * bi;
      ai += a * bi + c * br;
    }
    int a2 = base + (t * 64 + dd) * HW;
    Xr[a2] = ar + Xr[a2];
    Xi[a2] = ai + Xi[a2];
  }
}

// -------- Kernel E: complex MLP (LN -> 128->256 gelu -> 256->128) + resid --
__global__ __launch_bounds__(256) void k_mlp(
    const float* __restrict__ Xr, const float* __restrict__ Xi,
    const float* __restrict__ lnw, const float* __restrict__ lnb,
    const float* __restrict__ w1, const float* __restrict__ b1,
    const float* __restrict__ w2, const float* __restrict__ b2,
    float* __restrict__ out) {
  __shared__ float zn[128 * 33];
  __shared__ float hm[256 * 33];
  __shared__ float mu_s[32], rs_s[32];
  int bid = blockIdx.x;
  int wseg = bid & 1, h = (bid >> 1) & 63, bt = bid >> 7;
  int w0 = wseg * 32;
  int tid = threadIdx.x;
  int sbase = bt * DCH * HW + h * 64 + w0;
  for (int idx = tid; idx < 4096; idx += 256) {
    int f = idx >> 5, w = idx & 31;
    const float* p = (f < 64) ? Xr : Xi;
    zn[f * 33 + w] = p[sbase + (f & 63) * HW + w];
  }
  __syncthreads();
  if (tid < 32) {
    float s = 0.f, s2 = 0.f;
    for (int f = 0; f < 128; ++f) {
      float v = zn[f * 33 + tid]; s += v; s2 += v * v;
    }
    float mu = s * (1.f / 128.f);
    float var = s2 * (1.f / 128.f) - mu * mu;
    mu_s[tid] = mu; rs_s[tid] = rsqrtf(var + EPS);
  }
  __syncthreads();
  for (int idx = tid; idx < 4096; idx += 256) {
    int f = idx >> 5, w = idx & 31;
    zn[f * 33 + w] = (zn[f * 33 + w] - mu_s[w]) * rs_s[w] * lnw[f] + lnb[f];
  }
  __syncthreads();
  {
    float acc[32];
#pragma unroll
    for (int w = 0; w < 32; ++w) acc[w] = 0.f;
    for (int i = 0; i < 128; ++i) {
      float wv = w1[i * 256 + tid];
#pragma unroll
      for (int w = 0; w < 32; ++w) acc[w] += zn[i * 33 + w] * wv;
    }
    float bv = b1[tid];
#pragma unroll
    for (int w = 0; w < 32; ++w) {
      float v = acc[w] + bv;
      hm[tid * 33 + w] = 0.5f * v * (1.f + erff(v * 0.70710678118654752f));
    }
  }
  __syncthreads();
  {
    int o = tid & 127, wseg2 = tid >> 7;
    int wb = wseg2 * 16;
    float acc[16];
#pragma unroll
    for (int w = 0; w < 16; ++w) acc[w] = 0.f;
    for (int j = 0; j < 256; ++j) {
      float wv = w2[j * 128 + o];
#pragma unroll
      for (int w = 0; w < 16; ++w) acc[w] += hm[j * 33 + wb + w] * wv;
    }
    float bv = b2[o];
    int d = o & 63, part = o >> 6;
    const float* rp = part ? Xi : Xr;
#pragma unroll
    for (int w = 0; w < 16; ++w) {
      int widx = w0 + wb + w;
      int xa = bt * DCH * HW + d * HW + h * 64 + widx;
      out[xa * 2 + part] = acc[w] + bv + rp[xa];
    }
  }
}

extern "C" void kernel_launch(void* const* d_in, const int* in_sizes, int n_in,
                              void* d_out, int out_size, void* d_ws, size_t ws_size,
                              hipStream_t stream) {
  const float* x_real  = (const float*)d_in[0];
  const float* x_imag  = (const float*)d_in[1];
  const float* dt      = (const float*)d_in[2];
  const float* ln_s_w  = (const float*)d_in[3];
  const float* ln_s_b  = (const float*)d_in[4];
  const float* ln_t_w  = (const float*)d_in[5];
  const float* ln_t_b  = (const float*)d_in[6];
  const float* ln_m_w  = (const float*)d_in[7];
  const float* ln_m_b  = (const float*)d_in[8];
  const float* cw_r    = (const float*)d_in[9];
  const float* cw_i    = (const float*)d_in[10];
  const float* cb_r    = (const float*)d_in[11];
  const float* cb_i    = (const float*)d_in[12];
  const float* spec_wr = (const float*)d_in[13];
  const float* spec_wi = (const float*)d_in[14];
  const float* gate    = (const float*)d_in[15];
  const float* lam_re  = (const float*)d_in[16];
  const float* lam_im  = (const float*)d_in[17];
  const float* V_re    = (const float*)d_in[18];
  const float* V_im    = (const float*)d_in[19];
  const float* Vinv_re = (const float*)d_in[20];
  const float* Vinv_im = (const float*)d_in[21];
  const float* mlp_w1  = (const float*)d_in[22];
  const float* mlp_b1  = (const float*)d_in[23];
  const float* mlp_w2  = (const float*)d_in[24];
  const float* mlp_b2  = (const float*)d_in[25];

  float* out = (float*)d_out;
  float* W0r = (float*)d_ws;          // stage buffer (67 MB of ws)
  float* W0i = W0r + NELEM;
  float* W1r = out;                   // conv output parks in d_out (dead after kernel C)
  float* W1i = out + NELEM;

  k_ln_spatial<<<512, 256, 0, stream>>>(x_real, x_imag, ln_s_w, ln_s_b, W0r, W0i);
  k_conv<<<32768, 256, 0, stream>>>(W0r, W0i, cw_r, cw_i, cb_r, cb_i, W1r, W1i);
  k_fft_blend<<<2048, 256, 0, stream>>>(W0r, W0i, W1r, W1i, x_real, x_imag,
                                        spec_wr, spec_wi, gate);
  k_temporal<<<8192, 256, 0, stream>>>(W0r, W0i, dt, ln_t_w, ln_t_b,
                                       lam_re, lam_im, V_re, V_im, Vinv_re, Vinv_im);
  k_mlp<<<4096, 256, 0, stream>>>(W0r, W0i, ln_m_w, ln_m_b,
                                  mlp_w1, mlp_b1, mlp_w2, mlp_b2, out);
}

// Round 2
// 1655.416 us; speedup vs baseline: 1.8341x; 1.8341x over previous
//
#include <hip/hip_runtime.h>
#include <math.h>

#define NELEM 8388608   // B*T*D*H*W = 2*16*64*64*64
#define HW    4096
#define DCH   64
#define TT    16
#define EPS   1e-5f

typedef __attribute__((ext_vector_type(8))) short bfrag;   // 8 bf16 = 4 VGPRs
typedef __attribute__((ext_vector_type(16))) float accv;   // 16 fp32 acc

__device__ __forceinline__ unsigned short f2b(float f) {
  union { float f; unsigned u; } v; v.f = f;
  unsigned r = (v.u + 0x7FFF + ((v.u >> 16) & 1)) >> 16;
  return (unsigned short)r;
}
__device__ __forceinline__ float b2f(unsigned short h) {
  union { unsigned u; float f; } v; v.u = ((unsigned)h) << 16;
  return v.f;
}
__device__ __forceinline__ int rev6(int x) {
  return ((x & 1) << 5) | ((x & 2) << 3) | ((x & 4) << 1) |
         ((x & 8) >> 1) | ((x & 16) >> 3) | ((x & 32) >> 5);
}

// ---------------- Kernel W: weight prep -> Wt[tap][co=128][c=128] bf16 -----
__global__ __launch_bounds__(256) void k_wprep(
    const float* __restrict__ cwr, const float* __restrict__ cwi,
    unsigned short* __restrict__ Wt) {
  int gid = blockIdx.x * 256 + threadIdx.x;
  if (gid >= 9 * 128 * 128) return;
  int tap = gid >> 14;
  int rem = gid & 16383;
  int co = rem >> 7, c = rem & 127;
  int kh = tap / 3, kw = tap - kh * 3;
  int dout = co & 63, cin = c & 63;
  int widx = ((dout * 64 + cin) * 3 + kh) * 3 + kw;
  float v;
  if (co < 64) v = (c < 64) ? cwr[widx] : -cwi[widx];
  else         v = (c < 64) ? cwi[widx] :  cwr[widx];
  Wt[gid] = f2b(v);
}

// ---------------- Kernel A: spatial LN -> Xb[n][hw][c=128] bf16 ------------
__global__ __launch_bounds__(256) void k_ln_spatial(
    const float* __restrict__ xr, const float* __restrict__ xi,
    const float* __restrict__ w, const float* __restrict__ b,
    unsigned short* __restrict__ Xb) {
  int gid = blockIdx.x * 256 + threadIdx.x;   // 0..131071 = BT*HW
  int bt = gid >> 12;
  int hw = gid & 4095;
  size_t base = (size_t)bt * DCH * HW + hw;
  float vr[DCH], vi[DCH];
  float s = 0.f, s2 = 0.f;
#pragma unroll
  for (int d = 0; d < DCH; ++d) {
    float a = xr[base + d * HW];
    float c = xi[base + d * HW];
    vr[d] = a; vi[d] = c;
    s += a + c;
    s2 += a * a + c * c;
  }
  float mu = s * (1.f / 128.f);
  float var = s2 * (1.f / 128.f) - mu * mu;
  float rs = rsqrtf(var + EPS);
  unsigned short* dst = Xb + ((size_t)gid << 7);
#pragma unroll
  for (int k = 0; k < 8; ++k) {
    int4 o;
    unsigned short* op = (unsigned short*)&o;
#pragma unroll
    for (int j = 0; j < 8; ++j) {
      int d = k * 8 + j;
      op[j] = f2b((vr[d] - mu) * rs * w[d] + b[d]);
    }
    ((int4*)dst)[k] = o;
  }
#pragma unroll
  for (int k = 0; k < 8; ++k) {
    int4 o;
    unsigned short* op = (unsigned short*)&o;
#pragma unroll
    for (int j = 0; j < 8; ++j) {
      int d = k * 8 + j;
      op[j] = f2b((vi[d] - mu) * rs * w[64 + d] + b[64 + d]);
    }
    ((int4*)(dst + 64))[k] = o;
  }
}

// ---------------- Kernel B: implicit-GEMM MFMA conv ------------------------
// out[n][co][h][w] = sum_{c,kh,kw} Wt[tap][co][c] * Xpad[n][c][h+kh-1][w+kw-1]
// Block: 2 output rows x 64 cols (128 px), all 128 co. Grid: n(32) x rowgrp(32).
// LDS: Xs[row=4][kgrp=8][col=66][8c] bf16, per 64-channel half (re-staged).
__global__ __launch_bounds__(256, 4) void k_conv_mfma(
    const unsigned short* __restrict__ Xb,   // [n][hw][c=128]
    const unsigned short* __restrict__ Wt,   // [tap][co=128][c=128]
    const float* __restrict__ br, const float* __restrict__ bi,
    unsigned short* __restrict__ Cb) {       // [n][co=128][hw]
  __shared__ unsigned short Xs[4 * 8 * 66 * 8];   // 16896 ushort = 33,792 B
  int bid = blockIdx.x;
  int rg = bid & 31, n = bid >> 5;
  int r0 = rg << 1;
  int tid = threadIdx.x;
  int lane = tid & 63, wv = tid >> 6;
  int l31 = lane & 31, lhi = lane >> 5;
  int cobase = (wv >> 1) << 6;   // 0 or 64
  int prow = wv & 1;             // which of the 2 output rows

  accv acc[4] = {accv{}, accv{}, accv{}, accv{}};

  for (int q = tid; q < 2112; q += 256)
    ((int4*)Xs)[q] = make_int4(0, 0, 0, 0);
  __syncthreads();

  for (int half = 0; half < 2; ++half) {
    // stage 4 halo rows x 64 cols x 64 channels (this half)
    for (int q = tid; q < 2048; q += 256) {
      int cs = q & 7, col = (q >> 3) & 63, j = q >> 9;
      int gr = r0 - 1 + j;
      if (gr >= 0 && gr < 64) {
        const int4 v = *(const int4*)(Xb + (((size_t)n * 4096 + gr * 64 + col) << 7)
                                      + (half << 6) + (cs << 3));
        *(int4*)(Xs + (((j * 8 + cs) * 66 + col + 1) << 3)) = v;
      }
    }
    __syncthreads();
#pragma unroll
    for (int tap = 0; tap < 9; ++tap) {
      int kh = tap / 3, kw = tap - kh * 3;
      const unsigned short* wbase = Wt + tap * 16384 + (half << 6) + (lhi << 3);
#pragma unroll
      for (int ks = 0; ks < 4; ++ks) {
        bfrag af[2], bfv[2];
#pragma unroll
        for (int t2 = 0; t2 < 2; ++t2)
          af[t2] = *(const bfrag*)(wbase + ((size_t)(cobase + t2 * 32 + l31) << 7) + (ks << 4));
        const unsigned short* xrow = Xs + ((((prow + kh) * 8 + (ks * 2 + lhi)) * 66 + kw) << 3);
#pragma unroll
        for (int u = 0; u < 2; ++u)
          bfv[u] = *(const bfrag*)(xrow + ((u * 32 + l31) << 3));
#pragma unroll
        for (int t2 = 0; t2 < 2; ++t2)
#pragma unroll
          for (int u = 0; u < 2; ++u)
            acc[t2 * 2 + u] = __builtin_amdgcn_mfma_f32_32x32x16_bf16(
                af[t2], bfv[u], acc[t2 * 2 + u], 0, 0, 0);
      }
    }
    __syncthreads();
  }

  // epilogue: D col = lane&31 (px), row = (reg&3) + 8*(reg>>2) + 4*(lane>>5) (co)
#pragma unroll
  for (int t2 = 0; t2 < 2; ++t2) {
#pragma unroll
    for (int u = 0; u < 2; ++u) {
      accv A = acc[t2 * 2 + u];
      int hw = (r0 + prow) * 64 + u * 32 + l31;
#pragma unroll
      for (int rr = 0; rr < 16; ++rr) {
        int co = cobase + t2 * 32 + (rr & 3) + ((rr >> 2) << 3) + (lhi << 2);
        float bias = (co < 64) ? br[co] : bi[co & 63];
        Cb[(((size_t)n * 128 + co) << 12) + hw] = f2b(A[rr] + bias);
      }
    }
  }
}

// -------- Kernel C: FFT2 -> wspec -> iFFT2, blend with cliff + resid -------
__global__ __launch_bounds__(256) void k_fft_blend(
    float* __restrict__ Xr, float* __restrict__ Xi,        // W0 out
    const unsigned short* __restrict__ Xb,                 // ln out  [n][hw][c]
    const unsigned short* __restrict__ Cb,                 // cliff   [n][co][hw]
    const float* __restrict__ rr_, const float* __restrict__ ri_,
    const float* __restrict__ swr, const float* __restrict__ swi,
    const float* __restrict__ gate) {
  __shared__ float sr[64 * 65], si[64 * 65];
  const float PI = 3.14159265358979323846f;
  int bid = blockIdx.x;
  int ch = bid & 63;
  int n = bid >> 6;
  int base = bid << 12;
  int tid = threadIdx.x;
  for (int idx = tid; idx < 4096; idx += 256) {
    int r = idx >> 6, c = idx & 63;
    const unsigned short* xp = Xb + (((size_t)n * 4096 + idx) << 7) + ch;
    sr[r * 65 + c] = b2f(xp[0]);
    si[r * 65 + c] = b2f(xp[64]);
  }
  // forward rows, DIF (natural in, bit-reversed out)
  for (int s = 5; s >= 0; --s) {
    int half = 1 << s;
    __syncthreads();
    for (int idx = tid; idx < 2048; idx += 256) {
      int r = idx >> 5, j = idx & 31;
      int k = j & (half - 1), g = j >> s;
      int i0 = (g << (s + 1)) + k, i1 = i0 + half;
      float sv, cv; __sincosf(-PI * k / half, &sv, &cv);
      float ur = sr[r * 65 + i0], ui = si[r * 65 + i0];
      float vr = sr[r * 65 + i1], vi = si[r * 65 + i1];
      sr[r * 65 + i0] = ur + vr; si[r * 65 + i0] = ui + vi;
      float dr = ur - vr, di = ui - vi;
      sr[r * 65 + i1] = dr * cv - di * sv;
      si[r * 65 + i1] = dr * sv + di * cv;
    }
  }
  // forward cols, DIF
  for (int s = 5; s >= 0; --s) {
    int half = 1 << s;
    __syncthreads();
    for (int idx = tid; idx < 2048; idx += 256) {
      int c = idx & 63, j = idx >> 6;
      int k = j & (half - 1), g = j >> s;
      int i0 = (g << (s + 1)) + k, i1 = i0 + half;
      float sv, cv; __sincosf(-PI * k / half, &sv, &cv);
      float ur = sr[i0 * 65 + c], ui = si[i0 * 65 + c];
      float vr = sr[i1 * 65 + c], vi = si[i1 * 65 + c];
      sr[i0 * 65 + c] = ur + vr; si[i0 * 65 + c] = ui + vi;
      float dr = ur - vr, di = ui - vi;
      sr[i1 * 65 + c] = dr * cv - di * sv;
      si[i1 * 65 + c] = dr * sv + di * cv;
    }
  }
  __syncthreads();
  // multiply by wspec; LDS[r][c] = F[rev r][rev c]
  for (int idx = tid; idx < 4096; idx += 256) {
    int r = idx >> 6, c = idx & 63;
    int fr = rev6(r), fc = rev6(c);
    float wr = swr[ch * 4096 + fr * 64 + fc];
    float wi = swi[ch * 4096 + fr * 64 + fc];
    float a = sr[r * 65 + c], b = si[r * 65 + c];
    sr[r * 65 + c] = a * wr - b * wi;
    si[r * 65 + c] = a * wi + b * wr;
  }
  // inverse cols, DIT (bit-reversed in, natural out), conj twiddle
  for (int s = 0; s <= 5; ++s) {
    int half = 1 << s;
    __syncthreads();
    for (int idx = tid; idx < 2048; idx += 256) {
      int c = idx & 63, j = idx >> 6;
      int k = j & (half - 1), g = j >> s;
      int i0 = (g << (s + 1)) + k, i1 = i0 + half;
      float sv, cv; __sincosf(PI * k / half, &sv, &cv);
      float vr = sr[i1 * 65 + c], vi = si[i1 * 65 + c];
      float tr2 = vr * cv - vi * sv;
      float ti2 = vr * sv + vi * cv;
      float ur = sr[i0 * 65 + c], ui = si[i0 * 65 + c];
      sr[i0 * 65 + c] = ur + tr2; si[i0 * 65 + c] = ui + ti2;
      sr[i1 * 65 + c] = ur - tr2; si[i1 * 65 + c] = ui - ti2;
    }
  }
  // inverse rows, DIT
  for (int s = 0; s <= 5; ++s) {
    int half = 1 << s;
    __syncthreads();
    for (int idx = tid; idx < 2048; idx += 256) {
      int r = idx >> 5, j = idx & 31;
      int k = j & (half - 1), g = j >> s;
      int i0 = (g << (s + 1)) + k, i1 = i0 + half;
      float sv, cv; __sincosf(PI * k / half, &sv, &cv);
      float vr = sr[r * 65 + i1], vi = si[r * 65 + i1];
      float tr2 = vr * cv - vi * sv;
      float ti2 = vr * sv + vi * cv;
      float ur = sr[r * 65 + i0], ui = si[r * 65 + i0];
      sr[r * 65 + i0] = ur + tr2; si[r * 65 + i0] = ui + ti2;
      sr[r * 65 + i1] = ur - tr2; si[r * 65 + i1] = ui - ti2;
    }
  }
  __syncthreads();
  float g = gate[0];
  const float scale = 1.f / 4096.f;
  for (int idx = tid; idx < 4096; idx += 256) {
    int r = idx >> 6, c = idx & 63;
    float spr = sr[r * 65 + c] * scale, spi = si[r * 65 + c] * scale;
    int a = base + idx;
    float cr = b2f(Cb[(((size_t)n * 128 + ch) << 12) + idx]);
    float ci = b2f(Cb[(((size_t)n * 128 + 64 + ch) << 12) + idx]);
    Xr[a] = g * cr + (1.f - g) * spr + rr_[a];
    Xi[a] = g * ci + (1.f - g) * spi + ri_[a];
  }
}

// -------- Kernel D: temporal cnorm + eig proj + scan + back proj -----------
__global__ __launch_bounds__(256) void k_temporal(
    float* __restrict__ Xr, float* __restrict__ Xi,   // W0 in/out
    const float* __restrict__ dt,
    const float* __restrict__ lnw, const float* __restrict__ lnb,
    const float* __restrict__ lam_re, const float* __restrict__ lam_im,
    const float* __restrict__ V_re, const float* __restrict__ V_im,
    const float* __restrict__ Vi_re, const float* __restrict__ Vi_im) {
  __shared__ float xnr[16 * 65], xni[16 * 65];
  __shared__ float er[16 * 65], ei[16 * 65];
  __shared__ float Wr[64 * 65], Wi[64 * 65];   // Vinv
  __shared__ float Vr[64 * 65], Vm[64 * 65];   // V
  __shared__ float mu_s[16], rs_s[16];
  int bid = blockIdx.x;
  int b = bid >> 12;
  int hw = bid & 4095;
  int tid = threadIdx.x;
  for (int idx = tid; idx < 4096; idx += 256) {
    int r = idx >> 6, k = idx & 63;
    Wr[r * 65 + k] = Vi_re[idx]; Wi[r * 65 + k] = Vi_im[idx];
    Vr[r * 65 + k] = V_re[idx];  Vm[r * 65 + k] = V_im[idx];
  }
  int base = b * TT * DCH * HW + hw;
  for (int idx = tid; idx < 1024; idx += 256) {
    int t = idx >> 6, d = idx & 63;
    xnr[t * 65 + d] = Xr[base + idx * HW];
    xni[t * 65 + d] = Xi[base + idx * HW];
  }
  __syncthreads();
  if (tid < 16) {
    float s = 0.f, s2 = 0.f;
    for (int d = 0; d < 64; ++d) {
      float a = xnr[tid * 65 + d], c = xni[tid * 65 + d];
      s += a + c; s2 += a * a + c * c;
    }
    float mu = s * (1.f / 128.f);
    float var = s2 * (1.f / 128.f) - mu * mu;
    mu_s[tid] = mu; rs_s[tid] = rsqrtf(var + EPS);
  }
  __syncthreads();
  for (int idx = tid; idx < 1024; idx += 256) {
    int t = idx >> 6, d = idx & 63;
    xnr[t * 65 + d] = (xnr[t * 65 + d] - mu_s[t]) * rs_s[t] * lnw[d] + lnb[d];
    xni[t * 65 + d] = (xni[t * 65 + d] - mu_s[t]) * rs_s[t] * lnw[64 + d] + lnb[64 + d];
  }
  __syncthreads();
  int dd = tid & 63, tq = tid >> 6;
#pragma unroll
  for (int q = 0; q < 4; ++q) {
    int t = q * 4 + tq;
    float ar = 0.f, ai = 0.f;
    for (int k = 0; k < 64; ++k) {
      float a = xnr[t * 65 + k], c = xni[t * 65 + k];
      float br = Wr[dd * 65 + k], bi = Wi[dd * 65 + k];
      ar += a * br - c * bi;
      ai += a * bi + c * br;
    }
    er[t * 65 + dd] = ar; ei[t * 65 + dd] = ai;
  }
  __syncthreads();
  if (tid < 64) {
    int d = tid;
    float x0 = lam_re[d];
    float nl = -(x0 > 15.f ? x0 : log1pf(__expf(x0)));   // -softplus
    float li = lam_im[d];
    float hr = 0.f, hi = 0.f;
    for (int t = 0; t < 16; ++t) {
      float dtv = dt[b * 16 + t];
      float ea = __expf(nl * dtv);
      float sv, cv; __sincosf(li * dtv, &sv, &cv);
      float evr = ea * cv, evi = ea * sv;
      float nr = evr * hr - evi * hi + er[t * 65 + d];
      float ni = evr * hi + evi * hr + ei[t * 65 + d];
      hr = nr; hi = ni;
      er[t * 65 + d] = hr; ei[t * 65 + d] = hi;
    }
  }
  __syncthreads();
#pragma unroll
  for (int q = 0; q < 4; ++q) {
    int t = q * 4 + tq;
    float ar = 0.f, ai = 0.f;
    for (int k = 0; k < 64; ++k) {
      float a = er[t * 65 + k], c = ei[t * 65 + k];
      float br = Vr[dd * 65 + k], bi = Vm[dd * 65 + k];
      ar += a * br - c * bi;
      ai += a * bi + c * br;
    }
    int a2 = base + (t * 64 + dd) * HW;
    Xr[a2] = ar + Xr[a2];
    Xi[a2] = ai + Xi[a2];
  }
}

// -------- Kernel E: complex MLP (LN -> 128->256 gelu -> 256->128) + resid --
__global__ __launch_bounds__(256) void k_mlp(
    const float* __restrict__ Xr, const float* __restrict__ Xi,
    const float* __restrict__ lnw, const float* __restrict__ lnb,
    const float* __restrict__ w1, const float* __restrict__ b1,
    const float* __restrict__ w2, const float* __restrict__ b2,
    float* __restrict__ out) {
  __shared__ float zn[128 * 33];
  __shared__ float hm[256 * 33];
  __shared__ float mu_s[32], rs_s[32];
  int bid = blockIdx.x;
  int wseg = bid & 1, h = (bid >> 1) & 63, bt = bid >> 7;
  int w0 = wseg * 32;
  int tid = threadIdx.x;
  int sbase = bt * DCH * HW + h * 64 + w0;
  for (int idx = tid; idx < 4096; idx += 256) {
    int f = idx >> 5, w = idx & 31;
    const float* p = (f < 64) ? Xr : Xi;
    zn[f * 33 + w] = p[sbase + (f & 63) * HW + w];
  }
  __syncthreads();
  if (tid < 32) {
    float s = 0.f, s2 = 0.f;
    for (int f = 0; f < 128; ++f) {
      float v = zn[f * 33 + tid]; s += v; s2 += v * v;
    }
    float mu = s * (1.f / 128.f);
    float var = s2 * (1.f / 128.f) - mu * mu;
    mu_s[tid] = mu; rs_s[tid] = rsqrtf(var + EPS);
  }
  __syncthreads();
  for (int idx = tid; idx < 4096; idx += 256) {
    int f = idx >> 5, w = idx & 31;
    zn[f * 33 + w] = (zn[f * 33 + w] - mu_s[w]) * rs_s[w] * lnw[f] + lnb[f];
  }
  __syncthreads();
  {
    float acc[32];
#pragma unroll
    for (int w = 0; w < 32; ++w) acc[w] = 0.f;
    for (int i = 0; i < 128; ++i) {
      float wv = w1[i * 256 + tid];
#pragma unroll
      for (int w = 0; w < 32; ++w) acc[w] += zn[i * 33 + w] * wv;
    }
    float bv = b1[tid];
#pragma unroll
    for (int w = 0; w < 32; ++w) {
      float v = acc[w] + bv;
      hm[tid * 33 + w] = 0.5f * v * (1.f + erff(v * 0.70710678118654752f));
    }
  }
  __syncthreads();
  {
    int o = tid & 127, wseg2 = tid >> 7;
    int wb = wseg2 * 16;
    float acc[16];
#pragma unroll
    for (int w = 0; w < 16; ++w) acc[w] = 0.f;
    for (int j = 0; j < 256; ++j) {
      float wv = w2[j * 128 + o];
#pragma unroll
      for (int w = 0; w < 16; ++w) acc[w] += hm[j * 33 + wb + w] * wv;
    }
    float bv = b2[o];
    int d = o & 63, part = o >> 6;
    const float* rp = part ? Xi : Xr;
#pragma unroll
    for (int w = 0; w < 16; ++w) {
      int widx = w0 + wb + w;
      int xa = bt * DCH * HW + d * HW + h * 64 + widx;
      out[xa * 2 + part] = acc[w] + bv + rp[xa];
    }
  }
}

extern "C" void kernel_launch(void* const* d_in, const int* in_sizes, int n_in,
                              void* d_out, int out_size, void* d_ws, size_t ws_size,
                              hipStream_t stream) {
  const float* x_real  = (const float*)d_in[0];
  const float* x_imag  = (const float*)d_in[1];
  const float* dt      = (const float*)d_in[2];
  const float* ln_s_w  = (const float*)d_in[3];
  const float* ln_s_b  = (const float*)d_in[4];
  const float* ln_t_w  = (const float*)d_in[5];
  const float* ln_t_b  = (const float*)d_in[6];
  const float* ln_m_w  = (const float*)d_in[7];
  const float* ln_m_b  = (const float*)d_in[8];
  const float* cw_r    = (const float*)d_in[9];
  const float* cw_i    = (const float*)d_in[10];
  const float* cb_r    = (const float*)d_in[11];
  const float* cb_i    = (const float*)d_in[12];
  const float* spec_wr = (const float*)d_in[13];
  const float* spec_wi = (const float*)d_in[14];
  const float* gate    = (const float*)d_in[15];
  const float* lam_re  = (const float*)d_in[16];
  const float* lam_im  = (const float*)d_in[17];
  const float* V_re    = (const float*)d_in[18];
  const float* V_im    = (const float*)d_in[19];
  const float* Vinv_re = (const float*)d_in[20];
  const float* Vinv_im = (const float*)d_in[21];
  const float* mlp_w1  = (const float*)d_in[22];
  const float* mlp_b1  = (const float*)d_in[23];
  const float* mlp_w2  = (const float*)d_in[24];
  const float* mlp_b2  = (const float*)d_in[25];

  float* out = (float*)d_out;
  // d_out layout during pipeline: [Xb bf16: 16.7M ushort][Cb bf16: 16.7M ushort]
  unsigned short* Xb = (unsigned short*)d_out;
  unsigned short* Cb = Xb + (size_t)2 * NELEM;
  // d_ws: W0 fp32 stage buffer (written first by k_fft_blend).
  // Wt aliases the front of W0r: dead before fft_blend writes it.
  float* W0r = (float*)d_ws;
  float* W0i = W0r + NELEM;
  unsigned short* Wt = (unsigned short*)d_ws;

  k_wprep<<<576, 256, 0, stream>>>(cw_r, cw_i, Wt);
  k_ln_spatial<<<512, 256, 0, stream>>>(x_real, x_imag, ln_s_w, ln_s_b, Xb);
  k_conv_mfma<<<1024, 256, 0, stream>>>(Xb, Wt, cb_r, cb_i, Cb);
  k_fft_blend<<<2048, 256, 0, stream>>>(W0r, W0i, Xb, Cb, x_real, x_imag,
                                        spec_wr, spec_wi, gate);
  k_temporal<<<8192, 256, 0, stream>>>(W0r, W0i, dt, ln_t_w, ln_t_b,
                                       lam_re, lam_im, V_re, V_im, Vinv_re, Vinv_im);
  k_mlp<<<4096, 256, 0, stream>>>(W0r, W0i, ln_m_w, ln_m_b,
                                  mlp_w1, mlp_b1, mlp_w2, mlp_b2, out);
}

// Round 3
// 1144.458 us; speedup vs baseline: 2.6530x; 1.4465x over previous
//
#include <hip/hip_runtime.h>
#include <math.h>

#define NELEM 8388608   // B*T*D*H*W = 2*16*64*64*64
#define HW    4096
#define DCH   64
#define TT    16
#define EPS   1e-5f

typedef __attribute__((ext_vector_type(8))) short bfrag;   // 8 bf16 = 4 VGPRs
typedef __attribute__((ext_vector_type(16))) float accv;   // 16 fp32 acc

__device__ __forceinline__ unsigned short f2b(float f) {
  union { float f; unsigned u; } v; v.f = f;
  unsigned r = (v.u + 0x7FFF + ((v.u >> 16) & 1)) >> 16;
  return (unsigned short)r;
}
__device__ __forceinline__ float b2f(unsigned short h) {
  union { unsigned u; float f; } v; v.u = ((unsigned)h) << 16;
  return v.f;
}
__device__ __forceinline__ int rev6(int x) {
  return ((x & 1) << 5) | ((x & 2) << 3) | ((x & 4) << 1) |
         ((x & 8) >> 1) | ((x & 16) >> 3) | ((x & 32) >> 5);
}

// ---------------- Kernel W: weight prep -> Wt[tap][co=128][c=128] bf16 -----
__global__ __launch_bounds__(256) void k_wprep(
    const float* __restrict__ cwr, const float* __restrict__ cwi,
    unsigned short* __restrict__ Wt) {
  int gid = blockIdx.x * 256 + threadIdx.x;
  if (gid >= 9 * 128 * 128) return;
  int tap = gid >> 14;
  int rem = gid & 16383;
  int co = rem >> 7, c = rem & 127;
  int kh = tap / 3, kw = tap - kh * 3;
  int dout = co & 63, cin = c & 63;
  int widx = ((dout * 64 + cin) * 3 + kh) * 3 + kw;
  float v;
  if (co < 64) v = (c < 64) ? cwr[widx] : -cwi[widx];
  else         v = (c < 64) ? cwi[widx] :  cwr[widx];
  Wt[gid] = f2b(v);
}

// ------- Kernel V: temporal GEMM weights, MFMA-B layout [kg=16][n=128][8] --
// W1 from Vinv (xn -> eig), W2 from V (h -> out).
__global__ __launch_bounds__(256) void k_vprep(
    const float* __restrict__ Vre, const float* __restrict__ Vim,
    const float* __restrict__ Vire, const float* __restrict__ Viim,
    unsigned short* __restrict__ Wt1, unsigned short* __restrict__ Wt2) {
  int gid = blockIdx.x * 256 + threadIdx.x;   // 0..16383
  int j = gid & 7, n = (gid >> 3) & 127, kg = gid >> 10;
  int k = kg * 8 + j;
  int d = k & 63, dp = n & 63;
  float v1, v2;
  if (k < 64) {
    v1 = (n < 64) ? Vire[dp * 64 + d] : Viim[dp * 64 + d];
    v2 = (n < 64) ? Vre[dp * 64 + d] : Vim[dp * 64 + d];
  } else {
    v1 = (n < 64) ? -Viim[dp * 64 + d] : Vire[dp * 64 + d];
    v2 = (n < 64) ? -Vim[dp * 64 + d] : Vre[dp * 64 + d];
  }
  Wt1[gid] = f2b(v1); Wt2[gid] = f2b(v2);
}

// ---------------- Kernel A: spatial LN -> Xb[n][hw][c=128] bf16 ------------
__global__ __launch_bounds__(256) void k_ln_spatial(
    const float* __restrict__ xr, const float* __restrict__ xi,
    const float* __restrict__ w, const float* __restrict__ b,
    unsigned short* __restrict__ Xb) {
  int gid = blockIdx.x * 256 + threadIdx.x;   // 0..131071 = BT*HW
  int bt = gid >> 12;
  int hw = gid & 4095;
  size_t base = (size_t)bt * DCH * HW + hw;
  float vr[DCH], vi[DCH];
  float s = 0.f, s2 = 0.f;
#pragma unroll
  for (int d = 0; d < DCH; ++d) {
    float a = xr[base + d * HW];
    float c = xi[base + d * HW];
    vr[d] = a; vi[d] = c;
    s += a + c;
    s2 += a * a + c * c;
  }
  float mu = s * (1.f / 128.f);
  float var = s2 * (1.f / 128.f) - mu * mu;
  float rs = rsqrtf(var + EPS);
  unsigned short* dst = Xb + ((size_t)gid << 7);
#pragma unroll
  for (int k = 0; k < 8; ++k) {
    int4 o;
    unsigned short* op = (unsigned short*)&o;
#pragma unroll
    for (int j = 0; j < 8; ++j) {
      int d = k * 8 + j;
      op[j] = f2b((vr[d] - mu) * rs * w[d] + b[d]);
    }
    ((int4*)dst)[k] = o;
  }
#pragma unroll
  for (int k = 0; k < 8; ++k) {
    int4 o;
    unsigned short* op = (unsigned short*)&o;
#pragma unroll
    for (int j = 0; j < 8; ++j) {
      int d = k * 8 + j;
      op[j] = f2b((vi[d] - mu) * rs * w[64 + d] + b[64 + d]);
    }
    ((int4*)(dst + 64))[k] = o;
  }
}

// ---------------- Kernel B: implicit-GEMM MFMA conv ------------------------
__global__ __launch_bounds__(256, 4) void k_conv_mfma(
    const unsigned short* __restrict__ Xb,   // [n][hw][c=128]
    const unsigned short* __restrict__ Wt,   // [tap][co=128][c=128]
    const float* __restrict__ br, const float* __restrict__ bi,
    unsigned short* __restrict__ Cb) {       // [n][co=128][hw]
  __shared__ unsigned short Xs[4 * 8 * 66 * 8];   // 33,792 B
  int bid = blockIdx.x;
  int rg = bid & 31, n = bid >> 5;
  int r0 = rg << 1;
  int tid = threadIdx.x;
  int lane = tid & 63, wv = tid >> 6;
  int l31 = lane & 31, lhi = lane >> 5;
  int cobase = (wv >> 1) << 6;
  int prow = wv & 1;

  accv acc[4] = {accv{}, accv{}, accv{}, accv{}};

  for (int q = tid; q < 2112; q += 256)
    ((int4*)Xs)[q] = make_int4(0, 0, 0, 0);
  __syncthreads();

  for (int half = 0; half < 2; ++half) {
    for (int q = tid; q < 2048; q += 256) {
      int cs = q & 7, col = (q >> 3) & 63, j = q >> 9;
      int gr = r0 - 1 + j;
      if (gr >= 0 && gr < 64) {
        const int4 v = *(const int4*)(Xb + (((size_t)n * 4096 + gr * 64 + col) << 7)
                                      + (half << 6) + (cs << 3));
        *(int4*)(Xs + (((j * 8 + cs) * 66 + col + 1) << 3)) = v;
      }
    }
    __syncthreads();
#pragma unroll
    for (int tap = 0; tap < 9; ++tap) {
      int kh = tap / 3, kw = tap - kh * 3;
      const unsigned short* wbase = Wt + tap * 16384 + (half << 6) + (lhi << 3);
#pragma unroll
      for (int ks = 0; ks < 4; ++ks) {
        bfrag af[2], bfv[2];
#pragma unroll
        for (int t2 = 0; t2 < 2; ++t2)
          af[t2] = *(const bfrag*)(wbase + ((size_t)(cobase + t2 * 32 + l31) << 7) + (ks << 4));
        const unsigned short* xrow = Xs + ((((prow + kh) * 8 + (ks * 2 + lhi)) * 66 + kw) << 3);
#pragma unroll
        for (int u = 0; u < 2; ++u)
          bfv[u] = *(const bfrag*)(xrow + ((u * 32 + l31) << 3));
#pragma unroll
        for (int t2 = 0; t2 < 2; ++t2)
#pragma unroll
          for (int u = 0; u < 2; ++u)
            acc[t2 * 2 + u] = __builtin_amdgcn_mfma_f32_32x32x16_bf16(
                af[t2], bfv[u], acc[t2 * 2 + u], 0, 0, 0);
      }
    }
    __syncthreads();
  }

#pragma unroll
  for (int t2 = 0; t2 < 2; ++t2) {
#pragma unroll
    for (int u = 0; u < 2; ++u) {
      accv A = acc[t2 * 2 + u];
      int hw = (r0 + prow) * 64 + u * 32 + l31;
#pragma unroll
      for (int rr = 0; rr < 16; ++rr) {
        int co = cobase + t2 * 32 + (rr & 3) + ((rr >> 2) << 3) + (lhi << 2);
        float bias = (co < 64) ? br[co] : bi[co & 63];
        Cb[(((size_t)n * 128 + co) << 12) + hw] = f2b(A[rr] + bias);
      }
    }
  }
}

// -------- Kernel C: FFT2 -> wspec -> iFFT2, blend with cliff + resid -------
__global__ __launch_bounds__(256) void k_fft_blend(
    float* __restrict__ Xr, float* __restrict__ Xi,        // W0 out
    const unsigned short* __restrict__ Xb,                 // ln out  [n][hw][c]
    const unsigned short* __restrict__ Cb,                 // cliff   [n][co][hw]
    const float* __restrict__ rr_, const float* __restrict__ ri_,
    const float* __restrict__ swr, const float* __restrict__ swi,
    const float* __restrict__ gate) {
  __shared__ float sr[64 * 65], si[64 * 65];
  const float PI = 3.14159265358979323846f;
  int bid = blockIdx.x;
  int ch = bid & 63;
  int n = bid >> 6;
  int base = bid << 12;
  int tid = threadIdx.x;
  for (int idx = tid; idx < 4096; idx += 256) {
    int r = idx >> 6, c = idx & 63;
    const unsigned short* xp = Xb + (((size_t)n * 4096 + idx) << 7) + ch;
    sr[r * 65 + c] = b2f(xp[0]);
    si[r * 65 + c] = b2f(xp[64]);
  }
  for (int s = 5; s >= 0; --s) {
    int half = 1 << s;
    __syncthreads();
    for (int idx = tid; idx < 2048; idx += 256) {
      int r = idx >> 5, j = idx & 31;
      int k = j & (half - 1), g = j >> s;
      int i0 = (g << (s + 1)) + k, i1 = i0 + half;
      float sv, cv; __sincosf(-PI * k / half, &sv, &cv);
      float ur = sr[r * 65 + i0], ui = si[r * 65 + i0];
      float vr = sr[r * 65 + i1], vi = si[r * 65 + i1];
      sr[r * 65 + i0] = ur + vr; si[r * 65 + i0] = ui + vi;
      float dr = ur - vr, di = ui - vi;
      sr[r * 65 + i1] = dr * cv - di * sv;
      si[r * 65 + i1] = dr * sv + di * cv;
    }
  }
  for (int s = 5; s >= 0; --s) {
    int half = 1 << s;
    __syncthreads();
    for (int idx = tid; idx < 2048; idx += 256) {
      int c = idx & 63, j = idx >> 6;
      int k = j & (half - 1), g = j >> s;
      int i0 = (g << (s + 1)) + k, i1 = i0 + half;
      float sv, cv; __sincosf(-PI * k / half, &sv, &cv);
      float ur = sr[i0 * 65 + c], ui = si[i0 * 65 + c];
      float vr = sr[i1 * 65 + c], vi = si[i1 * 65 + c];
      sr[i0 * 65 + c] = ur + vr; si[i0 * 65 + c] = ui + vi;
      float dr = ur - vr, di = ui - vi;
      sr[i1 * 65 + c] = dr * cv - di * sv;
      si[i1 * 65 + c] = dr * sv + di * cv;
    }
  }
  __syncthreads();
  for (int idx = tid; idx < 4096; idx += 256) {
    int r = idx >> 6, c = idx & 63;
    int fr = rev6(r), fc = rev6(c);
    float wr = swr[ch * 4096 + fr * 64 + fc];
    float wi = swi[ch * 4096 + fr * 64 + fc];
    float a = sr[r * 65 + c], b = si[r * 65 + c];
    sr[r * 65 + c] = a * wr - b * wi;
    si[r * 65 + c] = a * wi + b * wr;
  }
  for (int s = 0; s <= 5; ++s) {
    int half = 1 << s;
    __syncthreads();
    for (int idx = tid; idx < 2048; idx += 256) {
      int c = idx & 63, j = idx >> 6;
      int k = j & (half - 1), g = j >> s;
      int i0 = (g << (s + 1)) + k, i1 = i0 + half;
      float sv, cv; __sincosf(PI * k / half, &sv, &cv);
      float vr = sr[i1 * 65 + c], vi = si[i1 * 65 + c];
      float tr2 = vr * cv - vi * sv;
      float ti2 = vr * sv + vi * cv;
      float ur = sr[i0 * 65 + c], ui = si[i0 * 65 + c];
      sr[i0 * 65 + c] = ur + tr2; si[i0 * 65 + c] = ui + ti2;
      sr[i1 * 65 + c] = ur - tr2; si[i1 * 65 + c] = ui - ti2;
    }
  }
  for (int s = 0; s <= 5; ++s) {
    int half = 1 << s;
    __syncthreads();
    for (int idx = tid; idx < 2048; idx += 256) {
      int r = idx >> 5, j = idx & 31;
      int k = j & (half - 1), g = j >> s;
      int i0 = (g << (s + 1)) + k, i1 = i0 + half;
      float sv, cv; __sincosf(PI * k / half, &sv, &cv);
      float vr = sr[r * 65 + i1], vi = si[r * 65 + i1];
      float tr2 = vr * cv - vi * sv;
      float ti2 = vr * sv + vi * cv;
      float ur = sr[r * 65 + i0], ui = si[r * 65 + i0];
      sr[r * 65 + i0] = ur + tr2; si[r * 65 + i0] = ui + ti2;
      sr[r * 65 + i1] = ur - tr2; si[r * 65 + i1] = ui - ti2;
    }
  }
  __syncthreads();
  float g = gate[0];
  const float scale = 1.f / 4096.f;
  for (int idx = tid; idx < 4096; idx += 256) {
    int r = idx >> 6, c = idx & 63;
    float spr = sr[r * 65 + c] * scale, spi = si[r * 65 + c] * scale;
    int a = base + idx;
    float cr = b2f(Cb[(((size_t)n * 128 + ch) << 12) + idx]);
    float ci = b2f(Cb[(((size_t)n * 128 + 64 + ch) << 12) + idx]);
    Xr[a] = g * cr + (1.f - g) * spr + rr_[a];
    Xi[a] = g * ci + (1.f - g) * spi + ri_[a];
  }
}

// -------- Kernel D: fused temporal (LN -> GEMM1 -> scan -> GEMM2 -> +res) --
// Block = (b, 4-px tile). M = 64 rows (t*4+px), K = N = 128.
// LDS: Asub 16KB (MFMA-A [kg16][m64][8]), Bsub 32KB ([kg16][n128][8]), Xe 32KB.
__global__ __launch_bounds__(256, 2) void k_temporal_mfma(
    float* __restrict__ Xr, float* __restrict__ Xi,   // W0 in/out
    const float* __restrict__ dt,
    const float* __restrict__ lnw, const float* __restrict__ lnb,
    const float* __restrict__ lam_re, const float* __restrict__ lam_im,
    const unsigned short* __restrict__ Wt1, const unsigned short* __restrict__ Wt2) {
  __shared__ unsigned short Asub[16 * 64 * 8];    // 16 KB
  __shared__ unsigned short Bsub[16 * 128 * 8];   // 32 KB
  __shared__ float Xe[64 * 128];                  // 32 KB
  int bid = blockIdx.x;
  int b = bid >> 10, tile = bid & 1023;
  int hw0 = tile * 4;
  int tid = threadIdx.x;
  int lane = tid & 63, wv = tid >> 6;
  int l31 = lane & 31, lhi = lane >> 5;
  size_t xbase = (size_t)b * TT * DCH * HW + hw0;

  // phase 1: stage raw X (rows r=t*4+px, cols c) + W1
#pragma unroll
  for (int q = 0; q < 8; ++q) {
    int item = tid + q * 256;          // t*128 + c
    int t = item >> 7, c = item & 127;
    int d = c & 63;
    const float* src = ((c >> 6) ? Xi : Xr) + xbase + ((size_t)t * 64 + d) * HW;
    float4 v = *(const float4*)src;
    Xe[(t * 4 + 0) * 128 + c] = v.x;
    Xe[(t * 4 + 1) * 128 + c] = v.y;
    Xe[(t * 4 + 2) * 128 + c] = v.z;
    Xe[(t * 4 + 3) * 128 + c] = v.w;
  }
#pragma unroll
  for (int q = 0; q < 8; ++q)
    ((int4*)Bsub)[tid + q * 256] = ((const int4*)Wt1)[tid + q * 256];
  __syncthreads();

  // phase 2: LN per row (4 threads/row, shuffle reduce) -> Asub bf16
  {
    int row = tid >> 2, seg = tid & 3;
    float s = 0.f, s2 = 0.f;
#pragma unroll
    for (int j = 0; j < 32; ++j) {
      float v = Xe[row * 128 + seg * 32 + j];
      s += v; s2 += v * v;
    }
    s += __shfl_xor(s, 1); s2 += __shfl_xor(s2, 1);
    s += __shfl_xor(s, 2); s2 += __shfl_xor(s2, 2);
    float mu = s * (1.f / 128.f);
    float var = s2 * (1.f / 128.f) - mu * mu;
    float rs = rsqrtf(var + EPS);
#pragma unroll
    for (int j = 0; j < 32; ++j) {
      int c = seg * 32 + j;
      float xnv = (Xe[row * 128 + c] - mu) * rs * lnw[c] + lnb[c];
      Asub[((c >> 3) * 64 + row) * 8 + (c & 7)] = f2b(xnv);
    }
  }
  __syncthreads();

  int mt = wv & 1, ntb = (wv >> 1) << 1;
  accv acc0 = accv{}, acc1 = accv{};
  // phase 3: GEMM1
#pragma unroll
  for (int ks = 0; ks < 8; ++ks) {
    int kg = ks * 2 + lhi;
    bfrag a = *(const bfrag*)(Asub + (kg * 64 + mt * 32 + l31) * 8);
    bfrag b0 = *(const bfrag*)(Bsub + (kg * 128 + ntb * 32 + l31) * 8);
    bfrag b1 = *(const bfrag*)(Bsub + (kg * 128 + (ntb + 1) * 32 + l31) * 8);
    acc0 = __builtin_amdgcn_mfma_f32_32x32x16_bf16(a, b0, acc0, 0, 0, 0);
    acc1 = __builtin_amdgcn_mfma_f32_32x32x16_bf16(a, b1, acc1, 0, 0, 0);
  }
  __syncthreads();

  // phase 4: acc -> Xe; restage W2 -> Bsub
#pragma unroll
  for (int rr = 0; rr < 16; ++rr) {
    int mrow = mt * 32 + (rr & 3) + ((rr >> 2) << 3) + (lhi << 2);
    Xe[mrow * 128 + ntb * 32 + l31] = acc0[rr];
    Xe[mrow * 128 + (ntb + 1) * 32 + l31] = acc1[rr];
  }
#pragma unroll
  for (int q = 0; q < 8; ++q)
    ((int4*)Bsub)[tid + q * 256] = ((const int4*)Wt2)[tid + q * 256];
  __syncthreads();

  // phase 5: complex scan per (px, d') chain, emit h as bf16 -> Asub
  {
    int px = tid >> 6, dp = tid & 63;
    float x0 = lam_re[dp];
    float nl = -(x0 > 15.f ? x0 : log1pf(__expf(x0)));
    float li = lam_im[dp];
    float hr = 0.f, hi = 0.f;
    int cR = dp, cI = 64 + dp;
    for (int t = 0; t < TT; ++t) {
      float dtv = dt[b * 16 + t];
      float ea = __expf(nl * dtv);
      float sv, cv; __sincosf(li * dtv, &sv, &cv);
      float evr = ea * cv, evi = ea * sv;
      int r = t * 4 + px;
      float xr_ = Xe[r * 128 + cR], xi_ = Xe[r * 128 + cI];
      float nhr = evr * hr - evi * hi + xr_;
      float nhi = evr * hi + evi * hr + xi_;
      hr = nhr; hi = nhi;
      Asub[((cR >> 3) * 64 + r) * 8 + (cR & 7)] = f2b(hr);
      Asub[((cI >> 3) * 64 + r) * 8 + (cI & 7)] = f2b(hi);
    }
  }
  __syncthreads();

  // phase 6: GEMM2
  acc0 = accv{}; acc1 = accv{};
#pragma unroll
  for (int ks = 0; ks < 8; ++ks) {
    int kg = ks * 2 + lhi;
    bfrag a = *(const bfrag*)(Asub + (kg * 64 + mt * 32 + l31) * 8);
    bfrag b0 = *(const bfrag*)(Bsub + (kg * 128 + ntb * 32 + l31) * 8);
    bfrag b1 = *(const bfrag*)(Bsub + (kg * 128 + (ntb + 1) * 32 + l31) * 8);
    acc0 = __builtin_amdgcn_mfma_f32_32x32x16_bf16(a, b0, acc0, 0, 0, 0);
    acc1 = __builtin_amdgcn_mfma_f32_32x32x16_bf16(a, b1, acc1, 0, 0, 0);
  }
  __syncthreads();

  // phase 7: acc -> Xe
#pragma unroll
  for (int rr = 0; rr < 16; ++rr) {
    int mrow = mt * 32 + (rr & 3) + ((rr >> 2) << 3) + (lhi << 2);
    Xe[mrow * 128 + ntb * 32 + l31] = acc0[rr];
    Xe[mrow * 128 + (ntb + 1) * 32 + l31] = acc1[rr];
  }
  __syncthreads();

  // phase 8: writeback + residual (float4 over px)
#pragma unroll
  for (int q = 0; q < 8; ++q) {
    int item = tid + q * 256;
    int t = item >> 7, c = item & 127;
    int d = c & 63;
    float* dst = ((c >> 6) ? Xi : Xr) + xbase + ((size_t)t * 64 + d) * HW;
    float4 rv = *(const float4*)dst;
    float4 o;
    o.x = Xe[(t * 4 + 0) * 128 + c] + rv.x;
    o.y = Xe[(t * 4 + 1) * 128 + c] + rv.y;
    o.z = Xe[(t * 4 + 2) * 128 + c] + rv.z;
    o.w = Xe[(t * 4 + 3) * 128 + c] + rv.w;
    *(float4*)dst = o;
  }
}

// -------- Kernel E: complex MLP (LN -> 128->256 gelu -> 256->128) + resid --
__global__ __launch_bounds__(256) void k_mlp(
    const float* __restrict__ Xr, const float* __restrict__ Xi,
    const float* __restrict__ lnw, const float* __restrict__ lnb,
    const float* __restrict__ w1, const float* __restrict__ b1,
    const float* __restrict__ w2, const float* __restrict__ b2,
    float* __restrict__ out) {
  __shared__ float zn[128 * 33];
  __shared__ float hm[256 * 33];
  __shared__ float mu_s[32], rs_s[32];
  int bid = blockIdx.x;
  int wseg = bid & 1, h = (bid >> 1) & 63, bt = bid >> 7;
  int w0 = wseg * 32;
  int tid = threadIdx.x;
  int sbase = bt * DCH * HW + h * 64 + w0;
  for (int idx = tid; idx < 4096; idx += 256) {
    int f = idx >> 5, w = idx & 31;
    const float* p = (f < 64) ? Xr : Xi;
    zn[f * 33 + w] = p[sbase + (f & 63) * HW + w];
  }
  __syncthreads();
  if (tid < 32) {
    float s = 0.f, s2 = 0.f;
    for (int f = 0; f < 128; ++f) {
      float v = zn[f * 33 + tid]; s += v; s2 += v * v;
    }
    float mu = s * (1.f / 128.f);
    float var = s2 * (1.f / 128.f) - mu * mu;
    mu_s[tid] = mu; rs_s[tid] = rsqrtf(var + EPS);
  }
  __syncthreads();
  for (int idx = tid; idx < 4096; idx += 256) {
    int f = idx >> 5, w = idx & 31;
    zn[f * 33 + w] = (zn[f * 33 + w] - mu_s[w]) * rs_s[w] * lnw[f] + lnb[f];
  }
  __syncthreads();
  {
    float acc[32];
#pragma unroll
    for (int w = 0; w < 32; ++w) acc[w] = 0.f;
    for (int i = 0; i < 128; ++i) {
      float wv = w1[i * 256 + tid];
#pragma unroll
      for (int w = 0; w < 32; ++w) acc[w] += zn[i * 33 + w] * wv;
    }
    float bv = b1[tid];
#pragma unroll
    for (int w = 0; w < 32; ++w) {
      float v = acc[w] + bv;
      hm[tid * 33 + w] = 0.5f * v * (1.f + erff(v * 0.70710678118654752f));
    }
  }
  __syncthreads();
  {
    int o = tid & 127, wseg2 = tid >> 7;
    int wb = wseg2 * 16;
    float acc[16];
#pragma unroll
    for (int w = 0; w < 16; ++w) acc[w] = 0.f;
    for (int j = 0; j < 256; ++j) {
      float wv = w2[j * 128 + o];
#pragma unroll
      for (int w = 0; w < 16; ++w) acc[w] += hm[j * 33 + wb + w] * wv;
    }
    float bv = b2[o];
    int d = o & 63, part = o >> 6;
    const float* rp = part ? Xi : Xr;
#pragma unroll
    for (int w = 0; w < 16; ++w) {
      int widx = w0 + wb + w;
      int xa = bt * DCH * HW + d * HW + h * 64 + widx;
      out[xa * 2 + part] = acc[w] + bv + rp[xa];
    }
  }
}

extern "C" void kernel_launch(void* const* d_in, const int* in_sizes, int n_in,
                              void* d_out, int out_size, void* d_ws, size_t ws_size,
                              hipStream_t stream) {
  const float* x_real  = (const float*)d_in[0];
  const float* x_imag  = (const float*)d_in[1];
  const float* dt      = (const float*)d_in[2];
  const float* ln_s_w  = (const float*)d_in[3];
  const float* ln_s_b  = (const float*)d_in[4];
  const float* ln_t_w  = (const float*)d_in[5];
  const float* ln_t_b  = (const float*)d_in[6];
  const float* ln_m_w  = (const float*)d_in[7];
  const float* ln_m_b  = (const float*)d_in[8];
  const float* cw_r    = (const float*)d_in[9];
  const float* cw_i    = (const float*)d_in[10];
  const float* cb_r    = (const float*)d_in[11];
  const float* cb_i    = (const float*)d_in[12];
  const float* spec_wr = (const float*)d_in[13];
  const float* spec_wi = (const float*)d_in[14];
  const float* gate    = (const float*)d_in[15];
  const float* lam_re  = (const float*)d_in[16];
  const float* lam_im  = (const float*)d_in[17];
  const float* V_re    = (const float*)d_in[18];
  const float* V_im    = (const float*)d_in[19];
  const float* Vinv_re = (const float*)d_in[20];
  const float* Vinv_im = (const float*)d_in[21];
  const float* mlp_w1  = (const float*)d_in[22];
  const float* mlp_b1  = (const float*)d_in[23];
  const float* mlp_w2  = (const float*)d_in[24];
  const float* mlp_b2  = (const float*)d_in[25];

  float* out = (float*)d_out;
  // d_out during pipeline: [Xb bf16: 2*NELEM ushort][Cb bf16: 2*NELEM ushort]
  unsigned short* Xb = (unsigned short*)d_out;
  unsigned short* Cb = Xb + (size_t)2 * NELEM;
  // After fft_blend, Xb region is dead -> reuse front for Wt1/Wt2 (32 KB each)
  unsigned short* Wt1 = Xb;
  unsigned short* Wt2 = Xb + 16384;
  // d_ws: W0 fp32 stage buffer. Conv-weight Wt aliases W0 front (dead before fft writes).
  float* W0r = (float*)d_ws;
  float* W0i = W0r + NELEM;
  unsigned short* Wt = (unsigned short*)d_ws;

  k_wprep<<<576, 256, 0, stream>>>(cw_r, cw_i, Wt);
  k_ln_spatial<<<512, 256, 0, stream>>>(x_real, x_imag, ln_s_w, ln_s_b, Xb);
  k_conv_mfma<<<1024, 256, 0, stream>>>(Xb, Wt, cb_r, cb_i, Cb);
  k_fft_blend<<<2048, 256, 0, stream>>>(W0r, W0i, Xb, Cb, x_real, x_imag,
                                        spec_wr, spec_wi, gate);
  k_vprep<<<64, 256, 0, stream>>>(V_re, V_im, Vinv_re, Vinv_im, Wt1, Wt2);
  k_temporal_mfma<<<2048, 256, 0, stream>>>(W0r, W0i, dt, ln_t_w, ln_t_b,
                                            lam_re, lam_im, Wt1, Wt2);
  k_mlp<<<4096, 256, 0, stream>>>(W0r, W0i, ln_m_w, ln_m_b,
                                  mlp_w1, mlp_b1, mlp_w2, mlp_b2, out);
}

// Round 4
// 722.314 us; speedup vs baseline: 4.2035x; 1.5844x over previous
//
#include <hip/hip_runtime.h>
#include <math.h>

#define NELEM 8388608   // B*T*D*H*W = 2*16*64*64*64
#define HW    4096
#define DCH   64
#define TT    16
#define EPS   1e-5f

typedef __attribute__((ext_vector_type(8))) short bfrag;   // 8 bf16 = 4 VGPRs
typedef __attribute__((ext_vector_type(16))) float accv;   // 16 fp32 acc

__device__ __forceinline__ unsigned short f2b(float f) {
  union { float f; unsigned u; } v; v.f = f;
  unsigned r = (v.u + 0x7FFF + ((v.u >> 16) & 1)) >> 16;
  return (unsigned short)r;
}
__device__ __forceinline__ float b2f(unsigned short h) {
  union { unsigned u; float f; } v; v.u = ((unsigned)h) << 16;
  return v.f;
}
__device__ __forceinline__ int rev6(int x) {
  return ((x & 1) << 5) | ((x & 2) << 3) | ((x & 4) << 1) |
         ((x & 8) >> 1) | ((x & 16) >> 3) | ((x & 32) >> 5);
}

// ---------------- Kernel W: weight prep -> Wt[tap][co=128][c=128] bf16 -----
__global__ __launch_bounds__(256) void k_wprep(
    const float* __restrict__ cwr, const float* __restrict__ cwi,
    unsigned short* __restrict__ Wt) {
  int gid = blockIdx.x * 256 + threadIdx.x;
  if (gid >= 9 * 128 * 128) return;
  int tap = gid >> 14;
  int rem = gid & 16383;
  int co = rem >> 7, c = rem & 127;
  int kh = tap / 3, kw = tap - kh * 3;
  int dout = co & 63, cin = c & 63;
  int widx = ((dout * 64 + cin) * 3 + kh) * 3 + kw;
  float v;
  if (co < 64) v = (c < 64) ? cwr[widx] : -cwi[widx];
  else         v = (c < 64) ? cwi[widx] :  cwr[widx];
  Wt[gid] = f2b(v);
}

// ------- Kernel V: temporal GEMM weights, MFMA-B layout [kg=16][n=128][8] --
__global__ __launch_bounds__(256) void k_vprep(
    const float* __restrict__ Vre, const float* __restrict__ Vim,
    const float* __restrict__ Vire, const float* __restrict__ Viim,
    unsigned short* __restrict__ Wt1, unsigned short* __restrict__ Wt2) {
  int gid = blockIdx.x * 256 + threadIdx.x;   // 0..16383
  int j = gid & 7, n = (gid >> 3) & 127, kg = gid >> 10;
  int k = kg * 8 + j;
  int d = k & 63, dp = n & 63;
  float v1, v2;
  if (k < 64) {
    v1 = (n < 64) ? Vire[dp * 64 + d] : Viim[dp * 64 + d];
    v2 = (n < 64) ? Vre[dp * 64 + d] : Vim[dp * 64 + d];
  } else {
    v1 = (n < 64) ? -Viim[dp * 64 + d] : Vire[dp * 64 + d];
    v2 = (n < 64) ? -Vim[dp * 64 + d] : Vre[dp * 64 + d];
  }
  Wt1[gid] = f2b(v1); Wt2[gid] = f2b(v2);
}

// ---------------- Kernel A: spatial LN -> Xb[n][hw][c=128] bf16 ------------
__global__ __launch_bounds__(256) void k_ln_spatial(
    const float* __restrict__ xr, const float* __restrict__ xi,
    const float* __restrict__ w, const float* __restrict__ b,
    unsigned short* __restrict__ Xb) {
  int gid = blockIdx.x * 256 + threadIdx.x;   // 0..131071 = BT*HW
  int bt = gid >> 12;
  int hw = gid & 4095;
  size_t base = (size_t)bt * DCH * HW + hw;
  float vr[DCH], vi[DCH];
  float s = 0.f, s2 = 0.f;
#pragma unroll
  for (int d = 0; d < DCH; ++d) {
    float a = xr[base + d * HW];
    float c = xi[base + d * HW];
    vr[d] = a; vi[d] = c;
    s += a + c;
    s2 += a * a + c * c;
  }
  float mu = s * (1.f / 128.f);
  float var = s2 * (1.f / 128.f) - mu * mu;
  float rs = rsqrtf(var + EPS);
  unsigned short* dst = Xb + ((size_t)gid << 7);
#pragma unroll
  for (int k = 0; k < 8; ++k) {
    int4 o;
    unsigned short* op = (unsigned short*)&o;
#pragma unroll
    for (int j = 0; j < 8; ++j) {
      int d = k * 8 + j;
      op[j] = f2b((vr[d] - mu) * rs * w[d] + b[d]);
    }
    ((int4*)dst)[k] = o;
  }
#pragma unroll
  for (int k = 0; k < 8; ++k) {
    int4 o;
    unsigned short* op = (unsigned short*)&o;
#pragma unroll
    for (int j = 0; j < 8; ++j) {
      int d = k * 8 + j;
      op[j] = f2b((vi[d] - mu) * rs * w[64 + d] + b[64 + d]);
    }
    ((int4*)(dst + 64))[k] = o;
  }
}

// ---------------- Kernel B: implicit-GEMM MFMA conv ------------------------
__global__ __launch_bounds__(256, 4) void k_conv_mfma(
    const unsigned short* __restrict__ Xb,   // [n][hw][c=128]
    const unsigned short* __restrict__ Wt,   // [tap][co=128][c=128]
    const float* __restrict__ br, const float* __restrict__ bi,
    unsigned short* __restrict__ Cb) {       // [n][co=128][hw]
  __shared__ unsigned short Xs[4 * 8 * 66 * 8];   // 33,792 B
  int bid = blockIdx.x;
  int rg = bid & 31, n = bid >> 5;
  int r0 = rg << 1;
  int tid = threadIdx.x;
  int lane = tid & 63, wv = tid >> 6;
  int l31 = lane & 31, lhi = lane >> 5;
  int cobase = (wv >> 1) << 6;
  int prow = wv & 1;

  accv acc[4] = {accv{}, accv{}, accv{}, accv{}};

  for (int q = tid; q < 2112; q += 256)
    ((int4*)Xs)[q] = make_int4(0, 0, 0, 0);
  __syncthreads();

  for (int half = 0; half < 2; ++half) {
    for (int q = tid; q < 2048; q += 256) {
      int cs = q & 7, col = (q >> 3) & 63, j = q >> 9;
      int gr = r0 - 1 + j;
      if (gr >= 0 && gr < 64) {
        const int4 v = *(const int4*)(Xb + (((size_t)n * 4096 + gr * 64 + col) << 7)
                                      + (half << 6) + (cs << 3));
        *(int4*)(Xs + (((j * 8 + cs) * 66 + col + 1) << 3)) = v;
      }
    }
    __syncthreads();
#pragma unroll
    for (int tap = 0; tap < 9; ++tap) {
      int kh = tap / 3, kw = tap - kh * 3;
      const unsigned short* wbase = Wt + tap * 16384 + (half << 6) + (lhi << 3);
#pragma unroll
      for (int ks = 0; ks < 4; ++ks) {
        bfrag af[2], bfv[2];
#pragma unroll
        for (int t2 = 0; t2 < 2; ++t2)
          af[t2] = *(const bfrag*)(wbase + ((size_t)(cobase + t2 * 32 + l31) << 7) + (ks << 4));
        const unsigned short* xrow = Xs + ((((prow + kh) * 8 + (ks * 2 + lhi)) * 66 + kw) << 3);
#pragma unroll
        for (int u = 0; u < 2; ++u)
          bfv[u] = *(const bfrag*)(xrow + ((u * 32 + l31) << 3));
#pragma unroll
        for (int t2 = 0; t2 < 2; ++t2)
#pragma unroll
          for (int u = 0; u < 2; ++u)
            acc[t2 * 2 + u] = __builtin_amdgcn_mfma_f32_32x32x16_bf16(
                af[t2], bfv[u], acc[t2 * 2 + u], 0, 0, 0);
      }
    }
    __syncthreads();
  }

#pragma unroll
  for (int t2 = 0; t2 < 2; ++t2) {
#pragma unroll
    for (int u = 0; u < 2; ++u) {
      accv A = acc[t2 * 2 + u];
      int hw = (r0 + prow) * 64 + u * 32 + l31;
#pragma unroll
      for (int rr = 0; rr < 16; ++rr) {
        int co = cobase + t2 * 32 + (rr & 3) + ((rr >> 2) << 3) + (lhi << 2);
        float bias = (co < 64) ? br[co] : bi[co & 63];
        Cb[(((size_t)n * 128 + co) << 12) + hw] = f2b(A[rr] + bias);
      }
    }
  }
}

// -------- Kernel C: FFT2 -> wspec -> iFFT2, blend with cliff + resid -------
__global__ __launch_bounds__(256) void k_fft_blend(
    float* __restrict__ Xr, float* __restrict__ Xi,        // W0 out
    const unsigned short* __restrict__ Xb,                 // ln out  [n][hw][c]
    const unsigned short* __restrict__ Cb,                 // cliff   [n][co][hw]
    const float* __restrict__ rr_, const float* __restrict__ ri_,
    const float* __restrict__ swr, const float* __restrict__ swi,
    const float* __restrict__ gate) {
  __shared__ float sr[64 * 65], si[64 * 65];
  const float PI = 3.14159265358979323846f;
  int bid = blockIdx.x;
  int ch = bid & 63;
  int n = bid >> 6;
  int base = bid << 12;
  int tid = threadIdx.x;
  for (int idx = tid; idx < 4096; idx += 256) {
    int r = idx >> 6, c = idx & 63;
    const unsigned short* xp = Xb + (((size_t)n * 4096 + idx) << 7) + ch;
    sr[r * 65 + c] = b2f(xp[0]);
    si[r * 65 + c] = b2f(xp[64]);
  }
  for (int s = 5; s >= 0; --s) {
    int half = 1 << s;
    __syncthreads();
    for (int idx = tid; idx < 2048; idx += 256) {
      int r = idx >> 5, j = idx & 31;
      int k = j & (half - 1), g = j >> s;
      int i0 = (g << (s + 1)) + k, i1 = i0 + half;
      float sv, cv; __sincosf(-PI * k / half, &sv, &cv);
      float ur = sr[r * 65 + i0], ui = si[r * 65 + i0];
      float vr = sr[r * 65 + i1], vi = si[r * 65 + i1];
      sr[r * 65 + i0] = ur + vr; si[r * 65 + i0] = ui + vi;
      float dr = ur - vr, di = ui - vi;
      sr[r * 65 + i1] = dr * cv - di * sv;
      si[r * 65 + i1] = dr * sv + di * cv;
    }
  }
  for (int s = 5; s >= 0; --s) {
    int half = 1 << s;
    __syncthreads();
    for (int idx = tid; idx < 2048; idx += 256) {
      int c = idx & 63, j = idx >> 6;
      int k = j & (half - 1), g = j >> s;
      int i0 = (g << (s + 1)) + k, i1 = i0 + half;
      float sv, cv; __sincosf(-PI * k / half, &sv, &cv);
      float ur = sr[i0 * 65 + c], ui = si[i0 * 65 + c];
      float vr = sr[i1 * 65 + c], vi = si[i1 * 65 + c];
      sr[i0 * 65 + c] = ur + vr; si[i0 * 65 + c] = ui + vi;
      float dr = ur - vr, di = ui - vi;
      sr[i1 * 65 + c] = dr * cv - di * sv;
      si[i1 * 65 + c] = dr * sv + di * cv;
    }
  }
  __syncthreads();
  for (int idx = tid; idx < 4096; idx += 256) {
    int r = idx >> 6, c = idx & 63;
    int fr = rev6(r), fc = rev6(c);
    float wr = swr[ch * 4096 + fr * 64 + fc];
    float wi = swi[ch * 4096 + fr * 64 + fc];
    float a = sr[r * 65 + c], b = si[r * 65 + c];
    sr[r * 65 + c] = a * wr - b * wi;
    si[r * 65 + c] = a * wi + b * wr;
  }
  for (int s = 0; s <= 5; ++s) {
    int half = 1 << s;
    __syncthreads();
    for (int idx = tid; idx < 2048; idx += 256) {
      int c = idx & 63, j = idx >> 6;
      int k = j & (half - 1), g = j >> s;
      int i0 = (g << (s + 1)) + k, i1 = i0 + half;
      float sv, cv; __sincosf(PI * k / half, &sv, &cv);
      float vr = sr[i1 * 65 + c], vi = si[i1 * 65 + c];
      float tr2 = vr * cv - vi * sv;
      float ti2 = vr * sv + vi * cv;
      float ur = sr[i0 * 65 + c], ui = si[i0 * 65 + c];
      sr[i0 * 65 + c] = ur + tr2; si[i0 * 65 + c] = ui + ti2;
      sr[i1 * 65 + c] = ur - tr2; si[i1 * 65 + c] = ui - ti2;
    }
  }
  for (int s = 0; s <= 5; ++s) {
    int half = 1 << s;
    __syncthreads();
    for (int idx = tid; idx < 2048; idx += 256) {
      int r = idx >> 5, j = idx & 31;
      int k = j & (half - 1), g = j >> s;
      int i0 = (g << (s + 1)) + k, i1 = i0 + half;
      float sv, cv; __sincosf(PI * k / half, &sv, &cv);
      float vr = sr[r * 65 + i1], vi = si[r * 65 + i1];
      float tr2 = vr * cv - vi * sv;
      float ti2 = vr * sv + vi * cv;
      float ur = sr[r * 65 + i0], ui = si[r * 65 + i0];
      sr[r * 65 + i0] = ur + tr2; si[r * 65 + i0] = ui + ti2;
      sr[r * 65 + i1] = ur - tr2; si[r * 65 + i1] = ui - ti2;
    }
  }
  __syncthreads();
  float g = gate[0];
  const float scale = 1.f / 4096.f;
  for (int idx = tid; idx < 4096; idx += 256) {
    int r = idx >> 6, c = idx & 63;
    float spr = sr[r * 65 + c] * scale, spi = si[r * 65 + c] * scale;
    int a = base + idx;
    float cr = b2f(Cb[(((size_t)n * 128 + ch) << 12) + idx]);
    float ci = b2f(Cb[(((size_t)n * 128 + 64 + ch) << 12) + idx]);
    Xr[a] = g * cr + (1.f - g) * spr + rr_[a];
    Xi[a] = g * ci + (1.f - g) * spi + ri_[a];
  }
}

// -------- Kernel D: fused temporal (LN -> GEMM1 -> scan -> GEMM2 -> +res) --
__global__ __launch_bounds__(256, 2) void k_temporal_mfma(
    float* __restrict__ Xr, float* __restrict__ Xi,   // W0 in/out
    const float* __restrict__ dt,
    const float* __restrict__ lnw, const float* __restrict__ lnb,
    const float* __restrict__ lam_re, const float* __restrict__ lam_im,
    const unsigned short* __restrict__ Wt1, const unsigned short* __restrict__ Wt2) {
  __shared__ unsigned short Asub[16 * 64 * 8];    // 16 KB
  __shared__ unsigned short Bsub[16 * 128 * 8];   // 32 KB
  __shared__ float Xe[64 * 128];                  // 32 KB
  int bid = blockIdx.x;
  int b = bid >> 10, tile = bid & 1023;
  int hw0 = tile * 4;
  int tid = threadIdx.x;
  int lane = tid & 63, wv = tid >> 6;
  int l31 = lane & 31, lhi = lane >> 5;
  size_t xbase = (size_t)b * TT * DCH * HW + hw0;

#pragma unroll
  for (int q = 0; q < 8; ++q) {
    int item = tid + q * 256;          // t*128 + c
    int t = item >> 7, c = item & 127;
    int d = c & 63;
    const float* src = ((c >> 6) ? Xi : Xr) + xbase + ((size_t)t * 64 + d) * HW;
    float4 v = *(const float4*)src;
    Xe[(t * 4 + 0) * 128 + c] = v.x;
    Xe[(t * 4 + 1) * 128 + c] = v.y;
    Xe[(t * 4 + 2) * 128 + c] = v.z;
    Xe[(t * 4 + 3) * 128 + c] = v.w;
  }
#pragma unroll
  for (int q = 0; q < 8; ++q)
    ((int4*)Bsub)[tid + q * 256] = ((const int4*)Wt1)[tid + q * 256];
  __syncthreads();

  {
    int row = tid >> 2, seg = tid & 3;
    float s = 0.f, s2 = 0.f;
#pragma unroll
    for (int j = 0; j < 32; ++j) {
      float v = Xe[row * 128 + seg * 32 + j];
      s += v; s2 += v * v;
    }
    s += __shfl_xor(s, 1); s2 += __shfl_xor(s2, 1);
    s += __shfl_xor(s, 2); s2 += __shfl_xor(s2, 2);
    float mu = s * (1.f / 128.f);
    float var = s2 * (1.f / 128.f) - mu * mu;
    float rs = rsqrtf(var + EPS);
#pragma unroll
    for (int j = 0; j < 32; ++j) {
      int c = seg * 32 + j;
      float xnv = (Xe[row * 128 + c] - mu) * rs * lnw[c] + lnb[c];
      Asub[((c >> 3) * 64 + row) * 8 + (c & 7)] = f2b(xnv);
    }
  }
  __syncthreads();

  int mt = wv & 1, ntb = (wv >> 1) << 1;
  accv acc0 = accv{}, acc1 = accv{};
#pragma unroll
  for (int ks = 0; ks < 8; ++ks) {
    int kg = ks * 2 + lhi;
    bfrag a = *(const bfrag*)(Asub + (kg * 64 + mt * 32 + l31) * 8);
    bfrag b0 = *(const bfrag*)(Bsub + (kg * 128 + ntb * 32 + l31) * 8);
    bfrag b1 = *(const bfrag*)(Bsub + (kg * 128 + (ntb + 1) * 32 + l31) * 8);
    acc0 = __builtin_amdgcn_mfma_f32_32x32x16_bf16(a, b0, acc0, 0, 0, 0);
    acc1 = __builtin_amdgcn_mfma_f32_32x32x16_bf16(a, b1, acc1, 0, 0, 0);
  }
  __syncthreads();

#pragma unroll
  for (int rr = 0; rr < 16; ++rr) {
    int mrow = mt * 32 + (rr & 3) + ((rr >> 2) << 3) + (lhi << 2);
    Xe[mrow * 128 + ntb * 32 + l31] = acc0[rr];
    Xe[mrow * 128 + (ntb + 1) * 32 + l31] = acc1[rr];
  }
#pragma unroll
  for (int q = 0; q < 8; ++q)
    ((int4*)Bsub)[tid + q * 256] = ((const int4*)Wt2)[tid + q * 256];
  __syncthreads();

  {
    int px = tid >> 6, dp = tid & 63;
    float x0 = lam_re[dp];
    float nl = -(x0 > 15.f ? x0 : log1pf(__expf(x0)));
    float li = lam_im[dp];
    float hr = 0.f, hi = 0.f;
    int cR = dp, cI = 64 + dp;
    for (int t = 0; t < TT; ++t) {
      float dtv = dt[b * 16 + t];
      float ea = __expf(nl * dtv);
      float sv, cv; __sincosf(li * dtv, &sv, &cv);
      float evr = ea * cv, evi = ea * sv;
      int r = t * 4 + px;
      float xr_ = Xe[r * 128 + cR], xi_ = Xe[r * 128 + cI];
      float nhr = evr * hr - evi * hi + xr_;
      float nhi = evr * hi + evi * hr + xi_;
      hr = nhr; hi = nhi;
      Asub[((cR >> 3) * 64 + r) * 8 + (cR & 7)] = f2b(hr);
      Asub[((cI >> 3) * 64 + r) * 8 + (cI & 7)] = f2b(hi);
    }
  }
  __syncthreads();

  acc0 = accv{}; acc1 = accv{};
#pragma unroll
  for (int ks = 0; ks < 8; ++ks) {
    int kg = ks * 2 + lhi;
    bfrag a = *(const bfrag*)(Asub + (kg * 64 + mt * 32 + l31) * 8);
    bfrag b0 = *(const bfrag*)(Bsub + (kg * 128 + ntb * 32 + l31) * 8);
    bfrag b1 = *(const bfrag*)(Bsub + (kg * 128 + (ntb + 1) * 32 + l31) * 8);
    acc0 = __builtin_amdgcn_mfma_f32_32x32x16_bf16(a, b0, acc0, 0, 0, 0);
    acc1 = __builtin_amdgcn_mfma_f32_32x32x16_bf16(a, b1, acc1, 0, 0, 0);
  }
  __syncthreads();

#pragma unroll
  for (int rr = 0; rr < 16; ++rr) {
    int mrow = mt * 32 + (rr & 3) + ((rr >> 2) << 3) + (lhi << 2);
    Xe[mrow * 128 + ntb * 32 + l31] = acc0[rr];
    Xe[mrow * 128 + (ntb + 1) * 32 + l31] = acc1[rr];
  }
  __syncthreads();

#pragma unroll
  for (int q = 0; q < 8; ++q) {
    int item = tid + q * 256;
    int t = item >> 7, c = item & 127;
    int d = c & 63;
    float* dst = ((c >> 6) ? Xi : Xr) + xbase + ((size_t)t * 64 + d) * HW;
    float4 rv = *(const float4*)dst;
    float4 o;
    o.x = Xe[(t * 4 + 0) * 128 + c] + rv.x;
    o.y = Xe[(t * 4 + 1) * 128 + c] + rv.y;
    o.z = Xe[(t * 4 + 2) * 128 + c] + rv.z;
    o.w = Xe[(t * 4 + 3) * 128 + c] + rv.w;
    *(float4*)dst = o;
  }
}

// -------- Kernel E: fused MFMA MLP (LN -> G1 -> gelu -> G2 -> +res) --------
// Block = (bt, 64-px tile). M=64, G1: K=128 N=256 (two 128-halves),
// G2: K=256 N=128 (two K-halves). Weights staged from fp32, bf16 B-layout.
__global__ __launch_bounds__(256, 2) void k_mlp_mfma(
    const float* __restrict__ Xr, const float* __restrict__ Xi,
    const float* __restrict__ lnw, const float* __restrict__ lnb,
    const float* __restrict__ w1, const float* __restrict__ b1,
    const float* __restrict__ w2, const float* __restrict__ b2,
    float* __restrict__ out) {
  __shared__ float bufA_f[64 * 128];              // 32 KB: Xe / Amid / Ld
  __shared__ unsigned short Bsub[16 * 128 * 8];   // 32 KB: weight half
  __shared__ unsigned short Asub[16 * 64 * 8];    // 16 KB: LN out, A-layout
  unsigned short* bufA_h = (unsigned short*)bufA_f;
  int bid = blockIdx.x;
  int bt = bid >> 6, tile = bid & 63;
  int hw0 = tile << 6;
  int tid = threadIdx.x;
  int lane = tid & 63, wv = tid >> 6;
  int l31 = lane & 31, lhi = lane >> 5;
  size_t base = (size_t)bt * DCH * HW + hw0;   // + d*HW + m

  // ---- phase 1: stage X fp32 -> bufA [c][m=64]; stage W1 half0 -> Bsub ----
#pragma unroll
  for (int q = 0; q < 8; ++q) {
    int item = q * 256 + tid;           // 2048 float4
    int m4 = item & 15, c = item >> 4;
    int d = c & 63;
    const float* src = ((c >> 6) ? Xi : Xr) + base + (size_t)d * HW + m4 * 4;
    *(float4*)(bufA_f + c * 64 + m4 * 4) = *(const float4*)src;
  }
  {
#pragma unroll
    for (int q = 0; q < 8; ++q) {
      int item = q * 256 + tid;         // 2048 int4
      int nn = item & 127, kg = item >> 7;
      const float* wp = w1 + (kg * 8) * 256 + nn;   // half0
      union { unsigned short u[8]; int4 v; } t;
#pragma unroll
      for (int j = 0; j < 8; ++j) t.u[j] = f2b(wp[j * 256]);
      *(int4*)(Bsub + (kg * 128 + nn) * 8) = t.v;
    }
  }
  __syncthreads();

  // ---- phase 2: LN per row -> Asub bf16 A-layout ----
  {
    int row = tid >> 2, seg = tid & 3;
    float s = 0.f, s2 = 0.f;
#pragma unroll
    for (int j = 0; j < 32; ++j) {
      float v = bufA_f[(seg * 32 + j) * 64 + row];
      s += v; s2 += v * v;
    }
    s += __shfl_xor(s, 1); s2 += __shfl_xor(s2, 1);
    s += __shfl_xor(s, 2); s2 += __shfl_xor(s2, 2);
    float mu = s * (1.f / 128.f);
    float var = s2 * (1.f / 128.f) - mu * mu;
    float rs = rsqrtf(var + EPS);
#pragma unroll
    for (int j = 0; j < 32; ++j) {
      int c = seg * 32 + j;
      float xnv = (bufA_f[c * 64 + row] - mu) * rs * lnw[c] + lnb[c];
      Asub[((c >> 3) * 64 + row) * 8 + (c & 7)] = f2b(xnv);
    }
  }
  __syncthreads();

  int nt = wv;                     // n-tile 0..3 within current 128 block
  int ng = nt * 32 + l31;          // 0..127
  // ---- GEMM1 halves: acc -> +b1 -> gelu -> Amid (bufA) A-layout ----
#pragma unroll
  for (int h = 0; h < 2; ++h) {
    if (h == 1) {
      __syncthreads();   // all waves done reading Bsub half0
#pragma unroll
      for (int q = 0; q < 8; ++q) {
        int item = q * 256 + tid;
        int nn = item & 127, kg = item >> 7;
        const float* wp = w1 + (kg * 8) * 256 + 128 + nn;
        union { unsigned short u[8]; int4 v; } t;
#pragma unroll
        for (int j = 0; j < 8; ++j) t.u[j] = f2b(wp[j * 256]);
        *(int4*)(Bsub + (kg * 128 + nn) * 8) = t.v;
      }
      __syncthreads();
    }
    accv g0 = accv{}, g1 = accv{};
#pragma unroll
    for (int ks = 0; ks < 8; ++ks) {
      int kg = ks * 2 + lhi;
      bfrag bfr = *(const bfrag*)(Bsub + (kg * 128 + ng) * 8);
      bfrag a0 = *(const bfrag*)(Asub + (kg * 64 + l31) * 8);
      bfrag a1 = *(const bfrag*)(Asub + (kg * 64 + 32 + l31) * 8);
      g0 = __builtin_amdgcn_mfma_f32_32x32x16_bf16(a0, bfr, g0, 0, 0, 0);
      g1 = __builtin_amdgcn_mfma_f32_32x32x16_bf16(a1, bfr, g1, 0, 0, 0);
    }
    float b1v = b1[h * 128 + ng];
    int kg2 = h * 16 + (ng >> 3), jj = ng & 7;
#pragma unroll
    for (int rr = 0; rr < 16; ++rr) {
      int mr = (rr & 3) + ((rr >> 2) << 3) + (lhi << 2);
      float v0 = g0[rr] + b1v;
      float v1 = g1[rr] + b1v;
      float e0 = 0.5f * v0 * (1.f + erff(v0 * 0.70710678118654752f));
      float e1 = 0.5f * v1 * (1.f + erff(v1 * 0.70710678118654752f));
      bufA_h[(kg2 * 64 + mr) * 8 + jj] = f2b(e0);
      bufA_h[(kg2 * 64 + 32 + mr) * 8 + jj] = f2b(e1);
    }
  }
  __syncthreads();

  // ---- GEMM2: K=256 in two halves (restage Bsub with W2) ----
  accv c0 = accv{}, c1 = accv{};
#pragma unroll
  for (int kh = 0; kh < 2; ++kh) {
    {
#pragma unroll
      for (int q = 0; q < 8; ++q) {
        int item = q * 256 + tid;
        int nn = item & 127, kg = item >> 7;
        const float* wp = w2 + (kh * 128 + kg * 8) * 128 + nn;
        union { unsigned short u[8]; int4 v; } t;
#pragma unroll
        for (int j = 0; j < 8; ++j) t.u[j] = f2b(wp[j * 128]);
        *(int4*)(Bsub + (kg * 128 + nn) * 8) = t.v;
      }
    }
    __syncthreads();
#pragma unroll
    for (int ks = 0; ks < 8; ++ks) {
      int kg = ks * 2 + lhi;
      int kga = kh * 16 + kg;
      bfrag bfr = *(const bfrag*)(Bsub + (kg * 128 + ng) * 8);
      bfrag a0 = *(const bfrag*)(bufA_h + (kga * 64 + l31) * 8);
      bfrag a1 = *(const bfrag*)(bufA_h + (kga * 64 + 32 + l31) * 8);
      c0 = __builtin_amdgcn_mfma_f32_32x32x16_bf16(a0, bfr, c0, 0, 0, 0);
      c1 = __builtin_amdgcn_mfma_f32_32x32x16_bf16(a1, bfr, c1, 0, 0, 0);
    }
    __syncthreads();   // before restage (kh=0) / before Ld writes (kh=1)
  }

  // ---- epilogue: acc -> Ld bf16 [n][66] (bufA reuse), then coalesced out --
  {
    float b2v = b2[ng];
#pragma unroll
    for (int rr = 0; rr < 16; ++rr) {
      int mr = (rr & 3) + ((rr >> 2) << 3) + (lhi << 2);
      bufA_h[ng * 66 + mr] = f2b(c0[rr] + b2v);
      bufA_h[ng * 66 + 32 + mr] = f2b(c1[rr] + b2v);
    }
  }
  __syncthreads();
#pragma unroll
  for (int q = 0; q < 4; ++q) {
    int item = q * 256 + tid;          // 1024: (d, m4)
    int m4 = item & 15, d = item >> 4;
    size_t xa = base + (size_t)d * HW + m4 * 4;
    float4 xr4 = *(const float4*)(Xr + xa);
    float4 xi4 = *(const float4*)(Xi + xa);
    int m = m4 * 4;
    float r0 = b2f(bufA_h[d * 66 + m]),     i0 = b2f(bufA_h[(64 + d) * 66 + m]);
    float r1 = b2f(bufA_h[d * 66 + m + 1]), i1 = b2f(bufA_h[(64 + d) * 66 + m + 1]);
    float r2 = b2f(bufA_h[d * 66 + m + 2]), i2 = b2f(bufA_h[(64 + d) * 66 + m + 2]);
    float r3 = b2f(bufA_h[d * 66 + m + 3]), i3 = b2f(bufA_h[(64 + d) * 66 + m + 3]);
    float4 o1, o2;
    o1.x = r0 + xr4.x; o1.y = i0 + xi4.x; o1.z = r1 + xr4.y; o1.w = i1 + xi4.y;
    o2.x = r2 + xr4.z; o2.y = i2 + xi4.z; o2.z = r3 + xr4.w; o2.w = i3 + xi4.w;
    *(float4*)(out + xa * 2) = o1;
    *(float4*)(out + xa * 2 + 4) = o2;
  }
}

extern "C" void kernel_launch(void* const* d_in, const int* in_sizes, int n_in,
                              void* d_out, int out_size, void* d_ws, size_t ws_size,
                              hipStream_t stream) {
  const float* x_real  = (const float*)d_in[0];
  const float* x_imag  = (const float*)d_in[1];
  const float* dt      = (const float*)d_in[2];
  const float* ln_s_w  = (const float*)d_in[3];
  const float* ln_s_b  = (const float*)d_in[4];
  const float* ln_t_w  = (const float*)d_in[5];
  const float* ln_t_b  = (const float*)d_in[6];
  const float* ln_m_w  = (const float*)d_in[7];
  const float* ln_m_b  = (const float*)d_in[8];
  const float* cw_r    = (const float*)d_in[9];
  const float* cw_i    = (const float*)d_in[10];
  const float* cb_r    = (const float*)d_in[11];
  const float* cb_i    = (const float*)d_in[12];
  const float* spec_wr = (const float*)d_in[13];
  const float* spec_wi = (const float*)d_in[14];
  const float* gate    = (const float*)d_in[15];
  const float* lam_re  = (const float*)d_in[16];
  const float* lam_im  = (const float*)d_in[17];
  const float* V_re    = (const float*)d_in[18];
  const float* V_im    = (const float*)d_in[19];
  const float* Vinv_re = (const float*)d_in[20];
  const float* Vinv_im = (const float*)d_in[21];
  const float* mlp_w1  = (const float*)d_in[22];
  const float* mlp_b1  = (const float*)d_in[23];
  const float* mlp_w2  = (const float*)d_in[24];
  const float* mlp_b2  = (const float*)d_in[25];

  float* out = (float*)d_out;
  // d_out during pipeline: [Xb bf16: 2*NELEM ushort][Cb bf16: 2*NELEM ushort]
  unsigned short* Xb = (unsigned short*)d_out;
  unsigned short* Cb = Xb + (size_t)2 * NELEM;
  // After fft_blend, Xb region is dead -> Wt1/Wt2 (32 KB each) for temporal
  unsigned short* Wt1 = Xb;
  unsigned short* Wt2 = Xb + 16384;
  // d_ws: W0 fp32 stage buffer. Conv-weight Wt aliases W0 front (dead before fft writes).
  float* W0r = (float*)d_ws;
  float* W0i = W0r + NELEM;
  unsigned short* Wt = (unsigned short*)d_ws;

  k_wprep<<<576, 256, 0, stream>>>(cw_r, cw_i, Wt);
  k_ln_spatial<<<512, 256, 0, stream>>>(x_real, x_imag, ln_s_w, ln_s_b, Xb);
  k_conv_mfma<<<1024, 256, 0, stream>>>(Xb, Wt, cb_r, cb_i, Cb);
  k_fft_blend<<<2048, 256, 0, stream>>>(W0r, W0i, Xb, Cb, x_real, x_imag,
                                        spec_wr, spec_wi, gate);
  k_vprep<<<64, 256, 0, stream>>>(V_re, V_im, Vinv_re, Vinv_im, Wt1, Wt2);
  k_temporal_mfma<<<2048, 256, 0, stream>>>(W0r, W0i, dt, ln_t_w, ln_t_b,
                                            lam_re, lam_im, Wt1, Wt2);
  k_mlp_mfma<<<2048, 256, 0, stream>>>(W0r, W0i, ln_m_w, ln_m_b,
                                       mlp_w1, mlp_b1, mlp_w2, mlp_b2, out);
}

// Round 5
// 551.841 us; speedup vs baseline: 5.5020x; 1.3089x over previous
//
#include <hip/hip_runtime.h>
#include <math.h>

#define NELEM 8388608   // B*T*D*H*W = 2*16*64*64*64
#define HW    4096
#define DCH   64
#define TT    16
#define EPS   1e-5f

typedef __attribute__((ext_vector_type(8))) short bfrag;   // 8 bf16 = 4 VGPRs
typedef __attribute__((ext_vector_type(16))) float accv;   // 16 fp32 acc

__device__ __forceinline__ unsigned short f2b(float f) {
  union { float f; unsigned u; } v; v.f = f;
  unsigned r = (v.u + 0x7FFF + ((v.u >> 16) & 1)) >> 16;
  return (unsigned short)r;
}
__device__ __forceinline__ float b2f(unsigned short h) {
  union { unsigned u; float f; } v; v.u = ((unsigned)h) << 16;
  return v.f;
}
__device__ __forceinline__ int rev6(int x) {
  return ((x & 1) << 5) | ((x & 2) << 3) | ((x & 4) << 1) |
         ((x & 8) >> 1) | ((x & 16) >> 3) | ((x & 32) >> 5);
}
// XCD-locality swizzle: put consecutive logical tiles on the SAME XCD
// (dispatch is round-robin bid%8 -> XCD). NB must be divisible by 8.
__device__ __forceinline__ int xcd_swizzle(int bid, int nb) {
  return (bid & 7) * (nb >> 3) + (bid >> 3);
}

// ---------------- Kernel W: weight prep -> Wt[tap][co=128][c=128] bf16 -----
__global__ __launch_bounds__(256) void k_wprep(
    const float* __restrict__ cwr, const float* __restrict__ cwi,
    unsigned short* __restrict__ Wt) {
  int gid = blockIdx.x * 256 + threadIdx.x;
  if (gid >= 9 * 128 * 128) return;
  int tap = gid >> 14;
  int rem = gid & 16383;
  int co = rem >> 7, c = rem & 127;
  int kh = tap / 3, kw = tap - kh * 3;
  int dout = co & 63, cin = c & 63;
  int widx = ((dout * 64 + cin) * 3 + kh) * 3 + kw;
  float v;
  if (co < 64) v = (c < 64) ? cwr[widx] : -cwi[widx];
  else         v = (c < 64) ? cwi[widx] :  cwr[widx];
  Wt[gid] = f2b(v);
}

// ------- Kernel V: temporal GEMM weights, MFMA-B layout [kg=16][n=128][8] --
__global__ __launch_bounds__(256) void k_vprep(
    const float* __restrict__ Vre, const float* __restrict__ Vim,
    const float* __restrict__ Vire, const float* __restrict__ Viim,
    unsigned short* __restrict__ Wt1, unsigned short* __restrict__ Wt2) {
  int gid = blockIdx.x * 256 + threadIdx.x;   // 0..16383
  int j = gid & 7, n = (gid >> 3) & 127, kg = gid >> 10;
  int k = kg * 8 + j;
  int d = k & 63, dp = n & 63;
  float v1, v2;
  if (k < 64) {
    v1 = (n < 64) ? Vire[dp * 64 + d] : Viim[dp * 64 + d];
    v2 = (n < 64) ? Vre[dp * 64 + d] : Vim[dp * 64 + d];
  } else {
    v1 = (n < 64) ? -Viim[dp * 64 + d] : Vire[dp * 64 + d];
    v2 = (n < 64) ? -Vim[dp * 64 + d] : Vre[dp * 64 + d];
  }
  Wt1[gid] = f2b(v1); Wt2[gid] = f2b(v2);
}

// ---------------- Kernel A: spatial LN -> Xb[n][hw][c=128] bf16 ------------
__global__ __launch_bounds__(256) void k_ln_spatial(
    const float* __restrict__ xr, const float* __restrict__ xi,
    const float* __restrict__ w, const float* __restrict__ b,
    unsigned short* __restrict__ Xb) {
  int gid = blockIdx.x * 256 + threadIdx.x;   // 0..131071 = BT*HW
  int bt = gid >> 12;
  int hw = gid & 4095;
  size_t base = (size_t)bt * DCH * HW + hw;
  float vr[DCH], vi[DCH];
  float s = 0.f, s2 = 0.f;
#pragma unroll
  for (int d = 0; d < DCH; ++d) {
    float a = xr[base + d * HW];
    float c = xi[base + d * HW];
    vr[d] = a; vi[d] = c;
    s += a + c;
    s2 += a * a + c * c;
  }
  float mu = s * (1.f / 128.f);
  float var = s2 * (1.f / 128.f) - mu * mu;
  float rs = rsqrtf(var + EPS);
  unsigned short* dst = Xb + ((size_t)gid << 7);
#pragma unroll
  for (int k = 0; k < 8; ++k) {
    int4 o;
    unsigned short* op = (unsigned short*)&o;
#pragma unroll
    for (int j = 0; j < 8; ++j) {
      int d = k * 8 + j;
      op[j] = f2b((vr[d] - mu) * rs * w[d] + b[d]);
    }
    ((int4*)dst)[k] = o;
  }
#pragma unroll
  for (int k = 0; k < 8; ++k) {
    int4 o;
    unsigned short* op = (unsigned short*)&o;
#pragma unroll
    for (int j = 0; j < 8; ++j) {
      int d = k * 8 + j;
      op[j] = f2b((vi[d] - mu) * rs * w[64 + d] + b[64 + d]);
    }
    ((int4*)(dst + 64))[k] = o;
  }
}

// ---------------- Kernel B: implicit-GEMM MFMA conv ------------------------
__global__ __launch_bounds__(256, 4) void k_conv_mfma(
    const unsigned short* __restrict__ Xb,   // [n][hw][c=128]
    const unsigned short* __restrict__ Wt,   // [tap][co=128][c=128]
    const float* __restrict__ br, const float* __restrict__ bi,
    unsigned short* __restrict__ Cb) {       // [n][co=128][hw]
  __shared__ unsigned short Xs[4 * 8 * 66 * 8];   // 33,792 B
  int bid = xcd_swizzle(blockIdx.x, 1024);   // same-n blocks share an XCD
  int rg = bid & 31, n = bid >> 5;
  int r0 = rg << 1;
  int tid = threadIdx.x;
  int lane = tid & 63, wv = tid >> 6;
  int l31 = lane & 31, lhi = lane >> 5;
  int cobase = (wv >> 1) << 6;
  int prow = wv & 1;

  accv acc[4] = {accv{}, accv{}, accv{}, accv{}};

  for (int q = tid; q < 2112; q += 256)
    ((int4*)Xs)[q] = make_int4(0, 0, 0, 0);
  __syncthreads();

  for (int half = 0; half < 2; ++half) {
    for (int q = tid; q < 2048; q += 256) {
      int cs = q & 7, col = (q >> 3) & 63, j = q >> 9;
      int gr = r0 - 1 + j;
      if (gr >= 0 && gr < 64) {
        const int4 v = *(const int4*)(Xb + (((size_t)n * 4096 + gr * 64 + col) << 7)
                                      + (half << 6) + (cs << 3));
        *(int4*)(Xs + (((j * 8 + cs) * 66 + col + 1) << 3)) = v;
      }
    }
    __syncthreads();
#pragma unroll
    for (int tap = 0; tap < 9; ++tap) {
      int kh = tap / 3, kw = tap - kh * 3;
      const unsigned short* wbase = Wt + tap * 16384 + (half << 6) + (lhi << 3);
#pragma unroll
      for (int ks = 0; ks < 4; ++ks) {
        bfrag af[2], bfv[2];
#pragma unroll
        for (int t2 = 0; t2 < 2; ++t2)
          af[t2] = *(const bfrag*)(wbase + ((size_t)(cobase + t2 * 32 + l31) << 7) + (ks << 4));
        const unsigned short* xrow = Xs + ((((prow + kh) * 8 + (ks * 2 + lhi)) * 66 + kw) << 3);
#pragma unroll
        for (int u = 0; u < 2; ++u)
          bfv[u] = *(const bfrag*)(xrow + ((u * 32 + l31) << 3));
#pragma unroll
        for (int t2 = 0; t2 < 2; ++t2)
#pragma unroll
          for (int u = 0; u < 2; ++u)
            acc[t2 * 2 + u] = __builtin_amdgcn_mfma_f32_32x32x16_bf16(
                af[t2], bfv[u], acc[t2 * 2 + u], 0, 0, 0);
      }
    }
    __syncthreads();
  }

#pragma unroll
  for (int t2 = 0; t2 < 2; ++t2) {
#pragma unroll
    for (int u = 0; u < 2; ++u) {
      accv A = acc[t2 * 2 + u];
      int hw = (r0 + prow) * 64 + u * 32 + l31;
#pragma unroll
      for (int rr = 0; rr < 16; ++rr) {
        int co = cobase + t2 * 32 + (rr & 3) + ((rr >> 2) << 3) + (lhi << 2);
        float bias = (co < 64) ? br[co] : bi[co & 63];
        Cb[(((size_t)n * 128 + co) << 12) + hw] = f2b(A[rr] + bias);
      }
    }
  }
}

// -------- Kernel C: FFT2 -> wspec -> iFFT2, blend with cliff + resid -------
__global__ __launch_bounds__(256) void k_fft_blend(
    float* __restrict__ Xr, float* __restrict__ Xi,        // W0 out
    const unsigned short* __restrict__ Xb,                 // ln out  [n][hw][c]
    const unsigned short* __restrict__ Cb,                 // cliff   [n][co][hw]
    const float* __restrict__ rr_, const float* __restrict__ ri_,
    const float* __restrict__ swr, const float* __restrict__ swi,
    const float* __restrict__ gate) {
  __shared__ float sr[64 * 65], si[64 * 65];
  const float PI = 3.14159265358979323846f;
  int bid = xcd_swizzle(blockIdx.x, 2048);   // same-n ch-blocks share an XCD
  int ch = bid & 63;
  int n = bid >> 6;
  int base = bid << 12;
  int tid = threadIdx.x;
  for (int idx = tid; idx < 4096; idx += 256) {
    int r = idx >> 6, c = idx & 63;
    const unsigned short* xp = Xb + (((size_t)n * 4096 + idx) << 7) + ch;
    sr[r * 65 + c] = b2f(xp[0]);
    si[r * 65 + c] = b2f(xp[64]);
  }
  for (int s = 5; s >= 0; --s) {
    int half = 1 << s;
    __syncthreads();
    for (int idx = tid; idx < 2048; idx += 256) {
      int r = idx >> 5, j = idx & 31;
      int k = j & (half - 1), g = j >> s;
      int i0 = (g << (s + 1)) + k, i1 = i0 + half;
      float sv, cv; __sincosf(-PI * k / half, &sv, &cv);
      float ur = sr[r * 65 + i0], ui = si[r * 65 + i0];
      float vr = sr[r * 65 + i1], vi = si[r * 65 + i1];
      sr[r * 65 + i0] = ur + vr; si[r * 65 + i0] = ui + vi;
      float dr = ur - vr, di = ui - vi;
      sr[r * 65 + i1] = dr * cv - di * sv;
      si[r * 65 + i1] = dr * sv + di * cv;
    }
  }
  for (int s = 5; s >= 0; --s) {
    int half = 1 << s;
    __syncthreads();
    for (int idx = tid; idx < 2048; idx += 256) {
      int c = idx & 63, j = idx >> 6;
      int k = j & (half - 1), g = j >> s;
      int i0 = (g << (s + 1)) + k, i1 = i0 + half;
      float sv, cv; __sincosf(-PI * k / half, &sv, &cv);
      float ur = sr[i0 * 65 + c], ui = si[i0 * 65 + c];
      float vr = sr[i1 * 65 + c], vi = si[i1 * 65 + c];
      sr[i0 * 65 + c] = ur + vr; si[i0 * 65 + c] = ui + vi;
      float dr = ur - vr, di = ui - vi;
      sr[i1 * 65 + c] = dr * cv - di * sv;
      si[i1 * 65 + c] = dr * sv + di * cv;
    }
  }
  __syncthreads();
  for (int idx = tid; idx < 4096; idx += 256) {
    int r = idx >> 6, c = idx & 63;
    int fr = rev6(r), fc = rev6(c);
    float wr = swr[ch * 4096 + fr * 64 + fc];
    float wi = swi[ch * 4096 + fr * 64 + fc];
    float a = sr[r * 65 + c], b = si[r * 65 + c];
    sr[r * 65 + c] = a * wr - b * wi;
    si[r * 65 + c] = a * wi + b * wr;
  }
  for (int s = 0; s <= 5; ++s) {
    int half = 1 << s;
    __syncthreads();
    for (int idx = tid; idx < 2048; idx += 256) {
      int c = idx & 63, j = idx >> 6;
      int k = j & (half - 1), g = j >> s;
      int i0 = (g << (s + 1)) + k, i1 = i0 + half;
      float sv, cv; __sincosf(PI * k / half, &sv, &cv);
      float vr = sr[i1 * 65 + c], vi = si[i1 * 65 + c];
      float tr2 = vr * cv - vi * sv;
      float ti2 = vr * sv + vi * cv;
      float ur = sr[i0 * 65 + c], ui = si[i0 * 65 + c];
      sr[i0 * 65 + c] = ur + tr2; si[i0 * 65 + c] = ui + ti2;
      sr[i1 * 65 + c] = ur - tr2; si[i1 * 65 + c] = ui - ti2;
    }
  }
  for (int s = 0; s <= 5; ++s) {
    int half = 1 << s;
    __syncthreads();
    for (int idx = tid; idx < 2048; idx += 256) {
      int r = idx >> 5, j = idx & 31;
      int k = j & (half - 1), g = j >> s;
      int i0 = (g << (s + 1)) + k, i1 = i0 + half;
      float sv, cv; __sincosf(PI * k / half, &sv, &cv);
      float vr = sr[r * 65 + i1], vi = si[r * 65 + i1];
      float tr2 = vr * cv - vi * sv;
      float ti2 = vr * sv + vi * cv;
      float ur = sr[r * 65 + i0], ui = si[r * 65 + i0];
      sr[r * 65 + i0] = ur + tr2; si[r * 65 + i0] = ui + ti2;
      sr[r * 65 + i1] = ur - tr2; si[r * 65 + i1] = ui - ti2;
    }
  }
  __syncthreads();
  float g = gate[0];
  const float scale = 1.f / 4096.f;
  for (int idx = tid; idx < 4096; idx += 256) {
    int r = idx >> 6, c = idx & 63;
    float spr = sr[r * 65 + c] * scale, spi = si[r * 65 + c] * scale;
    int a = base + idx;
    float cr = b2f(Cb[(((size_t)n * 128 + ch) << 12) + idx]);
    float ci = b2f(Cb[(((size_t)n * 128 + 64 + ch) << 12) + idx]);
    Xr[a] = g * cr + (1.f - g) * spr + rr_[a];
    Xi[a] = g * ci + (1.f - g) * spi + ri_[a];
  }
}

// -------- Kernel D: fused temporal (LN -> GEMM1 -> scan -> GEMM2 -> +res) --
__global__ __launch_bounds__(256, 2) void k_temporal_mfma(
    float* __restrict__ Xr, float* __restrict__ Xi,   // W0 in/out
    const float* __restrict__ dt,
    const float* __restrict__ lnw, const float* __restrict__ lnb,
    const float* __restrict__ lam_re, const float* __restrict__ lam_im,
    const unsigned short* __restrict__ Wt1, const unsigned short* __restrict__ Wt2) {
  __shared__ unsigned short Asub[16 * 64 * 8];    // 16 KB
  __shared__ unsigned short Bsub[16 * 128 * 8];   // 32 KB
  __shared__ float Xe[64 * 128];                  // 32 KB
  // swizzle: adjacent 4-px tiles (sharing 64B sectors) -> same XCD, near in time
  int bid = xcd_swizzle(blockIdx.x, 2048);
  int b = bid >> 10, tile = bid & 1023;
  int hw0 = tile * 4;
  int tid = threadIdx.x;
  int lane = tid & 63, wv = tid >> 6;
  int l31 = lane & 31, lhi = lane >> 5;
  size_t xbase = (size_t)b * TT * DCH * HW + hw0;

#pragma unroll
  for (int q = 0; q < 8; ++q) {
    int item = tid + q * 256;          // t*128 + c
    int t = item >> 7, c = item & 127;
    int d = c & 63;
    const float* src = ((c >> 6) ? Xi : Xr) + xbase + ((size_t)t * 64 + d) * HW;
    float4 v = *(const float4*)src;
    Xe[(t * 4 + 0) * 128 + c] = v.x;
    Xe[(t * 4 + 1) * 128 + c] = v.y;
    Xe[(t * 4 + 2) * 128 + c] = v.z;
    Xe[(t * 4 + 3) * 128 + c] = v.w;
  }
#pragma unroll
  for (int q = 0; q < 8; ++q)
    ((int4*)Bsub)[tid + q * 256] = ((const int4*)Wt1)[tid + q * 256];
  __syncthreads();

  {
    int row = tid >> 2, seg = tid & 3;
    float s = 0.f, s2 = 0.f;
#pragma unroll
    for (int j = 0; j < 32; ++j) {
      float v = Xe[row * 128 + seg * 32 + j];
      s += v; s2 += v * v;
    }
    s += __shfl_xor(s, 1); s2 += __shfl_xor(s2, 1);
    s += __shfl_xor(s, 2); s2 += __shfl_xor(s2, 2);
    float mu = s * (1.f / 128.f);
    float var = s2 * (1.f / 128.f) - mu * mu;
    float rs = rsqrtf(var + EPS);
#pragma unroll
    for (int j = 0; j < 32; ++j) {
      int c = seg * 32 + j;
      float xnv = (Xe[row * 128 + c] - mu) * rs * lnw[c] + lnb[c];
      Asub[((c >> 3) * 64 + row) * 8 + (c & 7)] = f2b(xnv);
    }
  }
  __syncthreads();

  int mt = wv & 1, ntb = (wv >> 1) << 1;
  accv acc0 = accv{}, acc1 = accv{};
#pragma unroll
  for (int ks = 0; ks < 8; ++ks) {
    int kg = ks * 2 + lhi;
    bfrag a = *(const bfrag*)(Asub + (kg * 64 + mt * 32 + l31) * 8);
    bfrag b0 = *(const bfrag*)(Bsub + (kg * 128 + ntb * 32 + l31) * 8);
    bfrag b1 = *(const bfrag*)(Bsub + (kg * 128 + (ntb + 1) * 32 + l31) * 8);
    acc0 = __builtin_amdgcn_mfma_f32_32x32x16_bf16(a, b0, acc0, 0, 0, 0);
    acc1 = __builtin_amdgcn_mfma_f32_32x32x16_bf16(a, b1, acc1, 0, 0, 0);
  }
  __syncthreads();

#pragma unroll
  for (int rr = 0; rr < 16; ++rr) {
    int mrow = mt * 32 + (rr & 3) + ((rr >> 2) << 3) + (lhi << 2);
    Xe[mrow * 128 + ntb * 32 + l31] = acc0[rr];
    Xe[mrow * 128 + (ntb + 1) * 32 + l31] = acc1[rr];
  }
#pragma unroll
  for (int q = 0; q < 8; ++q)
    ((int4*)Bsub)[tid + q * 256] = ((const int4*)Wt2)[tid + q * 256];
  __syncthreads();

  {
    int px = tid >> 6, dp = tid & 63;
    float x0 = lam_re[dp];
    float nl = -(x0 > 15.f ? x0 : log1pf(__expf(x0)));
    float li = lam_im[dp];
    float hr = 0.f, hi = 0.f;
    int cR = dp, cI = 64 + dp;
    for (int t = 0; t < TT; ++t) {
      float dtv = dt[b * 16 + t];
      float ea = __expf(nl * dtv);
      float sv, cv; __sincosf(li * dtv, &sv, &cv);
      float evr = ea * cv, evi = ea * sv;
      int r = t * 4 + px;
      float xr_ = Xe[r * 128 + cR], xi_ = Xe[r * 128 + cI];
      float nhr = evr * hr - evi * hi + xr_;
      float nhi = evr * hi + evi * hr + xi_;
      hr = nhr; hi = nhi;
      Asub[((cR >> 3) * 64 + r) * 8 + (cR & 7)] = f2b(hr);
      Asub[((cI >> 3) * 64 + r) * 8 + (cI & 7)] = f2b(hi);
    }
  }
  __syncthreads();

  acc0 = accv{}; acc1 = accv{};
#pragma unroll
  for (int ks = 0; ks < 8; ++ks) {
    int kg = ks * 2 + lhi;
    bfrag a = *(const bfrag*)(Asub + (kg * 64 + mt * 32 + l31) * 8);
    bfrag b0 = *(const bfrag*)(Bsub + (kg * 128 + ntb * 32 + l31) * 8);
    bfrag b1 = *(const bfrag*)(Bsub + (kg * 128 + (ntb + 1) * 32 + l31) * 8);
    acc0 = __builtin_amdgcn_mfma_f32_32x32x16_bf16(a, b0, acc0, 0, 0, 0);
    acc1 = __builtin_amdgcn_mfma_f32_32x32x16_bf16(a, b1, acc1, 0, 0, 0);
  }
  __syncthreads();

#pragma unroll
  for (int rr = 0; rr < 16; ++rr) {
    int mrow = mt * 32 + (rr & 3) + ((rr >> 2) << 3) + (lhi << 2);
    Xe[mrow * 128 + ntb * 32 + l31] = acc0[rr];
    Xe[mrow * 128 + (ntb + 1) * 32 + l31] = acc1[rr];
  }
  __syncthreads();

#pragma unroll
  for (int q = 0; q < 8; ++q) {
    int item = tid + q * 256;
    int t = item >> 7, c = item & 127;
    int d = c & 63;
    float* dst = ((c >> 6) ? Xi : Xr) + xbase + ((size_t)t * 64 + d) * HW;
    float4 rv = *(const float4*)dst;
    float4 o;
    o.x = Xe[(t * 4 + 0) * 128 + c] + rv.x;
    o.y = Xe[(t * 4 + 1) * 128 + c] + rv.y;
    o.z = Xe[(t * 4 + 2) * 128 + c] + rv.z;
    o.w = Xe[(t * 4 + 3) * 128 + c] + rv.w;
    *(float4*)dst = o;
  }
}

// -------- Kernel E: fused MFMA MLP (LN -> G1 -> gelu -> G2 -> +res) --------
__global__ __launch_bounds__(256, 2) void k_mlp_mfma(
    const float* __restrict__ Xr, const float* __restrict__ Xi,
    const float* __restrict__ lnw, const float* __restrict__ lnb,
    const float* __restrict__ w1, const float* __restrict__ b1,
    const float* __restrict__ w2, const float* __restrict__ b2,
    float* __restrict__ out) {
  __shared__ float bufA_f[64 * 128];              // 32 KB: Xe / Amid / Ld
  __shared__ unsigned short Bsub[16 * 128 * 8];   // 32 KB: weight half
  __shared__ unsigned short Asub[16 * 64 * 8];    // 16 KB: LN out, A-layout
  unsigned short* bufA_h = (unsigned short*)bufA_f;
  int bid = blockIdx.x;
  int bt = bid >> 6, tile = bid & 63;
  int hw0 = tile << 6;
  int tid = threadIdx.x;
  int lane = tid & 63, wv = tid >> 6;
  int l31 = lane & 31, lhi = lane >> 5;
  size_t base = (size_t)bt * DCH * HW + hw0;   // + d*HW + m

#pragma unroll
  for (int q = 0; q < 8; ++q) {
    int item = q * 256 + tid;           // 2048 float4
    int m4 = item & 15, c = item >> 4;
    int d = c & 63;
    const float* src = ((c >> 6) ? Xi : Xr) + base + (size_t)d * HW + m4 * 4;
    *(float4*)(bufA_f + c * 64 + m4 * 4) = *(const float4*)src;
  }
  {
#pragma unroll
    for (int q = 0; q < 8; ++q) {
      int item = q * 256 + tid;         // 2048 int4
      int nn = item & 127, kg = item >> 7;
      const float* wp = w1 + (kg * 8) * 256 + nn;   // half0
      union { unsigned short u[8]; int4 v; } t;
#pragma unroll
      for (int j = 0; j < 8; ++j) t.u[j] = f2b(wp[j * 256]);
      *(int4*)(Bsub + (kg * 128 + nn) * 8) = t.v;
    }
  }
  __syncthreads();

  {
    int row = tid >> 2, seg = tid & 3;
    float s = 0.f, s2 = 0.f;
#pragma unroll
    for (int j = 0; j < 32; ++j) {
      float v = bufA_f[(seg * 32 + j) * 64 + row];
      s += v; s2 += v * v;
    }
    s += __shfl_xor(s, 1); s2 += __shfl_xor(s2, 1);
    s += __shfl_xor(s, 2); s2 += __shfl_xor(s2, 2);
    float mu = s * (1.f / 128.f);
    float var = s2 * (1.f / 128.f) - mu * mu;
    float rs = rsqrtf(var + EPS);
#pragma unroll
    for (int j = 0; j < 32; ++j) {
      int c = seg * 32 + j;
      float xnv = (bufA_f[c * 64 + row] - mu) * rs * lnw[c] + lnb[c];
      Asub[((c >> 3) * 64 + row) * 8 + (c & 7)] = f2b(xnv);
    }
  }
  __syncthreads();

  int nt = wv;
  int ng = nt * 32 + l31;
#pragma unroll
  for (int h = 0; h < 2; ++h) {
    if (h == 1) {
      __syncthreads();
#pragma unroll
      for (int q = 0; q < 8; ++q) {
        int item = q * 256 + tid;
        int nn = item & 127, kg = item >> 7;
        const float* wp = w1 + (kg * 8) * 256 + 128 + nn;
        union { unsigned short u[8]; int4 v; } t;
#pragma unroll
        for (int j = 0; j < 8; ++j) t.u[j] = f2b(wp[j * 256]);
        *(int4*)(Bsub + (kg * 128 + nn) * 8) = t.v;
      }
      __syncthreads();
    }
    accv g0 = accv{}, g1 = accv{};
#pragma unroll
    for (int ks = 0; ks < 8; ++ks) {
      int kg = ks * 2 + lhi;
      bfrag bfr = *(const bfrag*)(Bsub + (kg * 128 + ng) * 8);
      bfrag a0 = *(const bfrag*)(Asub + (kg * 64 + l31) * 8);
      bfrag a1 = *(const bfrag*)(Asub + (kg * 64 + 32 + l31) * 8);
      g0 = __builtin_amdgcn_mfma_f32_32x32x16_bf16(a0, bfr, g0, 0, 0, 0);
      g1 = __builtin_amdgcn_mfma_f32_32x32x16_bf16(a1, bfr, g1, 0, 0, 0);
    }
    float b1v = b1[h * 128 + ng];
    int kg2 = h * 16 + (ng >> 3), jj = ng & 7;
#pragma unroll
    for (int rr = 0; rr < 16; ++rr) {
      int mr = (rr & 3) + ((rr >> 2) << 3) + (lhi << 2);
      float v0 = g0[rr] + b1v;
      float v1 = g1[rr] + b1v;
      float e0 = 0.5f * v0 * (1.f + erff(v0 * 0.70710678118654752f));
      float e1 = 0.5f * v1 * (1.f + erff(v1 * 0.70710678118654752f));
      bufA_h[(kg2 * 64 + mr) * 8 + jj] = f2b(e0);
      bufA_h[(kg2 * 64 + 32 + mr) * 8 + jj] = f2b(e1);
    }
  }
  __syncthreads();

  accv c0 = accv{}, c1 = accv{};
#pragma unroll
  for (int kh = 0; kh < 2; ++kh) {
    {
#pragma unroll
      for (int q = 0; q < 8; ++q) {
        int item = q * 256 + tid;
        int nn = item & 127, kg = item >> 7;
        const float* wp = w2 + (kh * 128 + kg * 8) * 128 + nn;
        union { unsigned short u[8]; int4 v; } t;
#pragma unroll
        for (int j = 0; j < 8; ++j) t.u[j] = f2b(wp[j * 128]);
        *(int4*)(Bsub + (kg * 128 + nn) * 8) = t.v;
      }
    }
    __syncthreads();
#pragma unroll
    for (int ks = 0; ks < 8; ++ks) {
      int kg = ks * 2 + lhi;
      int kga = kh * 16 + kg;
      bfrag bfr = *(const bfrag*)(Bsub + (kg * 128 + ng) * 8);
      bfrag a0 = *(const bfrag*)(bufA_h + (kga * 64 + l31) * 8);
      bfrag a1 = *(const bfrag*)(bufA_h + (kga * 64 + 32 + l31) * 8);
      c0 = __builtin_amdgcn_mfma_f32_32x32x16_bf16(a0, bfr, c0, 0, 0, 0);
      c1 = __builtin_amdgcn_mfma_f32_32x32x16_bf16(a1, bfr, c1, 0, 0, 0);
    }
    __syncthreads();
  }

  {
    float b2v = b2[ng];
#pragma unroll
    for (int rr = 0; rr < 16; ++rr) {
      int mr = (rr & 3) + ((rr >> 2) << 3) + (lhi << 2);
      bufA_h[ng * 66 + mr] = f2b(c0[rr] + b2v);
      bufA_h[ng * 66 + 32 + mr] = f2b(c1[rr] + b2v);
    }
  }
  __syncthreads();
#pragma unroll
  for (int q = 0; q < 4; ++q) {
    int item = q * 256 + tid;          // 1024: (d, m4)
    int m4 = item & 15, d = item >> 4;
    size_t xa = base + (size_t)d * HW + m4 * 4;
    float4 xr4 = *(const float4*)(Xr + xa);
    float4 xi4 = *(const float4*)(Xi + xa);
    int m = m4 * 4;
    float r0 = b2f(bufA_h[d * 66 + m]),     i0 = b2f(bufA_h[(64 + d) * 66 + m]);
    float r1 = b2f(bufA_h[d * 66 + m + 1]), i1 = b2f(bufA_h[(64 + d) * 66 + m + 1]);
    float r2 = b2f(bufA_h[d * 66 + m + 2]), i2 = b2f(bufA_h[(64 + d) * 66 + m + 2]);
    float r3 = b2f(bufA_h[d * 66 + m + 3]), i3 = b2f(bufA_h[(64 + d) * 66 + m + 3]);
    float4 o1, o2;
    o1.x = r0 + xr4.x; o1.y = i0 + xi4.x; o1.z = r1 + xr4.y; o1.w = i1 + xi4.y;
    o2.x = r2 + xr4.z; o2.y = i2 + xi4.z; o2.z = r3 + xr4.w; o2.w = i3 + xi4.w;
    *(float4*)(out + xa * 2) = o1;
    *(float4*)(out + xa * 2 + 4) = o2;
  }
}

extern "C" void kernel_launch(void* const* d_in, const int* in_sizes, int n_in,
                              void* d_out, int out_size, void* d_ws, size_t ws_size,
                              hipStream_t stream) {
  const float* x_real  = (const float*)d_in[0];
  const float* x_imag  = (const float*)d_in[1];
  const float* dt      = (const float*)d_in[2];
  const float* ln_s_w  = (const float*)d_in[3];
  const float* ln_s_b  = (const float*)d_in[4];
  const float* ln_t_w  = (const float*)d_in[5];
  const float* ln_t_b  = (const float*)d_in[6];
  const float* ln_m_w  = (const float*)d_in[7];
  const float* ln_m_b  = (const float*)d_in[8];
  const float* cw_r    = (const float*)d_in[9];
  const float* cw_i    = (const float*)d_in[10];
  const float* cb_r    = (const float*)d_in[11];
  const float* cb_i    = (const float*)d_in[12];
  const float* spec_wr = (const float*)d_in[13];
  const float* spec_wi = (const float*)d_in[14];
  const float* gate    = (const float*)d_in[15];
  const float* lam_re  = (const float*)d_in[16];
  const float* lam_im  = (const float*)d_in[17];
  const float* V_re    = (const float*)d_in[18];
  const float* V_im    = (const float*)d_in[19];
  const float* Vinv_re = (const float*)d_in[20];
  const float* Vinv_im = (const float*)d_in[21];
  const float* mlp_w1  = (const float*)d_in[22];
  const float* mlp_b1  = (const float*)d_in[23];
  const float* mlp_w2  = (const float*)d_in[24];
  const float* mlp_b2  = (const float*)d_in[25];

  float* out = (float*)d_out;
  unsigned short* Xb = (unsigned short*)d_out;
  unsigned short* Cb = Xb + (size_t)2 * NELEM;
  unsigned short* Wt1 = Xb;
  unsigned short* Wt2 = Xb + 16384;
  float* W0r = (float*)d_ws;
  float* W0i = W0r + NELEM;
  unsigned short* Wt = (unsigned short*)d_ws;

  k_wprep<<<576, 256, 0, stream>>>(cw_r, cw_i, Wt);
  k_ln_spatial<<<512, 256, 0, stream>>>(x_real, x_imag, ln_s_w, ln_s_b, Xb);
  k_conv_mfma<<<1024, 256, 0, stream>>>(Xb, Wt, cb_r, cb_i, Cb);
  k_fft_blend<<<2048, 256, 0, stream>>>(W0r, W0i, Xb, Cb, x_real, x_imag,
                                        spec_wr, spec_wi, gate);
  k_vprep<<<64, 256, 0, stream>>>(V_re, V_im, Vinv_re, Vinv_im, Wt1, Wt2);
  k_temporal_mfma<<<2048, 256, 0, stream>>>(W0r, W0i, dt, ln_t_w, ln_t_b,
                                            lam_re, lam_im, Wt1, Wt2);
  k_mlp_mfma<<<2048, 256, 0, stream>>>(W0r, W0i, ln_m_w, ln_m_b,
                                       mlp_w1, mlp_b1, mlp_w2, mlp_b2, out);
}